// Round 9
// baseline (696.002 us; speedup 1.0000x reference)
//
#include <hip/hip_runtime.h>
#include <hip/hip_bf16.h>
#include <math.h>
#include <cstddef>
#include <stdint.h>

#define NN 20000
#define EE 320000
#define RR 8
#define PP 100000
#define NR (NN * RR)   // 160000 = 625*256

typedef __hip_bfloat16 bf16;
typedef __attribute__((ext_vector_type(8))) short short8;
typedef __attribute__((ext_vector_type(4))) short short4v;
typedef __attribute__((ext_vector_type(4))) float floatx4;
typedef __attribute__((ext_vector_type(4))) int intx4;

__device__ __forceinline__ float b2f(bf16 v) { return __bfloat162float(v); }
__device__ __forceinline__ bf16 f2b(float v) { return __float2bfloat16(v); }
__device__ __forceinline__ float bits2f(unsigned short u) {
  unsigned int i = ((unsigned int)u) << 16; float f; __builtin_memcpy(&f, &i, 4); return f;
}
__device__ __forceinline__ short f2bits(float f) {
  bf16 h = __float2bfloat16(f); short s; __builtin_memcpy(&s, &h, 2); return s;
}
// fast tanh-form gelu: x*sigmoid(2t), t = 0.79788456*(x + 0.044715*x^3).
// 0.5*(1+tanh(t)) == 1/(1+e^{-2t}) == rcp(1 + 2^{-2.885390082*t}).
// max |delta| vs exact-erf gelu ~3e-4 << bf16 quantization noise.
__device__ __forceinline__ float gelu_f(float x) {
  float t = x * (0.7978845608f + 0.0356774081f * x * x);
  float s = exp2f(-2.885390082f * t);
  return x * __builtin_amdgcn_rcpf(1.f + s);
}
// async global->LDS, 16B per lane; lds base wave-uniform, lane i lands at base+i*16
__device__ __forceinline__ void async_copy16(void* lds, const void* g) {
  __builtin_amdgcn_global_load_lds((const __attribute__((address_space(1))) void*)g,
                                   (__attribute__((address_space(3))) void*)lds, 16, 0, 0);
}
// swizzled fragment address, [rows][64] bf16 tile (stride 64): chunk q lives at q^(row&7)
__device__ __forceinline__ const short8* frag_at(const bf16* base, int row, int q) {
  return (const short8*)(base + row * 64 + (((q) ^ (row & 7)) << 3));
}
// stride-256 variant (col64 = 64-col group base), and stride-128 variant (qg = global chunk)
__device__ __forceinline__ const short8* frag256(const bf16* base, int row, int col64, int q) {
  return (const short8*)(base + row * 256 + col64 + (((q) ^ (row & 7)) << 3));
}
__device__ __forceinline__ int idx128(int row, int qg) {
  return row * 128 + ((qg >> 3) << 6) + (((qg & 7) ^ (row & 7)) << 3);
}

// ---------------- CSR build ----------------
__global__ void hist_k(const int* __restrict__ dst, const int* __restrict__ et,
                       int* __restrict__ counts) {
  int e = blockIdx.x * 256 + threadIdx.x;
  if (e >= EE) return;
  atomicAdd(&counts[dst[e] * RR + et[e]], 1);
}

__global__ void scan1_k(const int* __restrict__ counts, int* __restrict__ prefix,
                        int* __restrict__ bsums) {
  __shared__ int tmp[256];
  int i = blockIdx.x * 256 + threadIdx.x;
  int v = counts[i];
  tmp[threadIdx.x] = v; __syncthreads();
  for (int off = 1; off < 256; off <<= 1) {
    int x = (threadIdx.x >= off) ? tmp[threadIdx.x - off] : 0;
    __syncthreads();
    tmp[threadIdx.x] += x;
    __syncthreads();
  }
  prefix[i] = tmp[threadIdx.x] - v;
  if (threadIdx.x == 255) bsums[blockIdx.x] = tmp[255];
}

__global__ void scan2_k(int* __restrict__ bsums, int nb) {
  __shared__ int tmp[256];
  __shared__ int carry;
  if (threadIdx.x == 0) carry = 0;
  __syncthreads();
  for (int base = 0; base < nb; base += 256) {
    int i = base + threadIdx.x;
    int v = (i < nb) ? bsums[i] : 0;
    tmp[threadIdx.x] = v; __syncthreads();
    for (int off = 1; off < 256; off <<= 1) {
      int x = (threadIdx.x >= off) ? tmp[threadIdx.x - off] : 0;
      __syncthreads();
      tmp[threadIdx.x] += x;
      __syncthreads();
    }
    int c = carry;
    if (i < nb) bsums[i] = c + tmp[threadIdx.x] - v;
    __syncthreads();
    if (threadIdx.x == 255) carry = c + tmp[255];
    __syncthreads();
  }
}

__global__ void scan3_k(int* __restrict__ prefix, const int* __restrict__ bsums) {
  int i = blockIdx.x * 256 + threadIdx.x;
  prefix[i] += bsums[blockIdx.x];
}

__global__ void scatter_k(const int* __restrict__ src, const int* __restrict__ dst,
                          const int* __restrict__ et, const int* __restrict__ segstart,
                          int* __restrict__ cursor, int* __restrict__ ssrc) {
  int e = blockIdx.x * 256 + threadIdx.x;
  if (e >= EE) return;
  int s = dst[e] * RR + et[e];
  int pos = atomicAdd(&cursor[s], 1);
  ssrc[segstart[s] + pos] = src[e];
}

// ---------------- small prep kernels ----------------
__global__ void cvt_bf16_k(const float* __restrict__ in, bf16* __restrict__ out, int n) {
  int i = blockIdx.x * 256 + threadIdx.x;
  if (i < n) out[i] = f2b(in[i]);
}

__global__ void softmax4_k(const float* r0, const float* r1, const float* r2,
                           const float* r3, float* __restrict__ a) {
  if (threadIdx.x == 0) {
    const float* rs[4] = {r0, r1, r2, r3};
    for (int l = 0; l < 4; ++l) {
      float mx = -1e30f;
      for (int i = 0; i < RR; ++i) mx = fmaxf(mx, rs[l][i]);
      float e[RR]; float s = 0.f;
      for (int i = 0; i < RR; ++i) { e[i] = expf(rs[l][i] - mx); s += e[i]; }
      for (int i = 0; i < RR; ++i) a[l * RR + i] = e[i] / s;
    }
  }
}

// all small weight transposes batched into ONE launch (was 6 launches)
__global__ void prep_small_k(const float* __restrict__ res0, const float* __restrict__ res3,
                             const float* __restrict__ dW0, const float* __restrict__ dW1,
                             const float* __restrict__ dW2,
                             bf16* __restrict__ RES0T, bf16* __restrict__ RES3T,
                             bf16* __restrict__ WAT, bf16* __restrict__ WPE,
                             bf16* __restrict__ DW1T, bf16* __restrict__ DW2T) {
  int idx = blockIdx.x * 256 + threadIdx.x;
  if (idx < 32768) {                         // res0 [128][256] -> T
    int r = idx >> 8, c = idx & 255;
    RES0T[(size_t)c * 128 + r] = f2b(res0[idx]);
  } else if (idx < 65536) {                  // res3 [256][128] -> T
    int i2 = idx - 32768; int r = i2 >> 7, c = i2 & 127;
    RES3T[(size_t)c * 256 + r] = f2b(res3[i2]);
  } else if (idx < 98304) {                  // WA = dW0[0:128] [128][256] -> T
    int i2 = idx - 65536; int r = i2 >> 8, c = i2 & 255;
    WAT[(size_t)c * 128 + r] = f2b(dW0[i2]);
  } else if (idx < 131072) {                 // WPE: prod|diff combined K
    int i2 = idx - 98304; int k = i2 >> 8, o = i2 & 255;
    WPE[(size_t)o * 256 + k] = f2b(dW0[128 * 256 + i2]);
    WPE[(size_t)o * 256 + 128 + k] = f2b(dW0[256 * 256 + i2]);
  } else if (idx < 163840) {                 // dW1 [256][128] -> T
    int i2 = idx - 131072; int r = i2 >> 7, c = i2 & 127;
    DW1T[(size_t)c * 256 + r] = f2b(dW1[i2]);
  } else if (idx < 172032) {                 // dW2 [128][64] -> T
    int i2 = idx - 163840; int r = i2 >> 6, c = i2 & 63;
    DW2T[(size_t)c * 128 + r] = f2b(dW2[i2]);
  }
}

// coalesced: consecutive threads -> consecutive o -> basis reads coalesced
__global__ void prep_w_k(const float* __restrict__ basis, const float* __restrict__ att,
                         const float* __restrict__ root, const float* __restrict__ a,
                         bf16* __restrict__ Wt, int ic, int icsh, int oc, int ocsh) {
  int idx = blockIdx.x * 256 + threadIdx.x;
  int cols = 9 * ic;
  if (idx >= cols * oc) return;
  int o = idx & (oc - 1);
  int col = idx >> ocsh;
  int r = col >> icsh;
  int k = col & (ic - 1);
  float val;
  if (r < RR) {
    float acc = 0.f;
    for (int bb = 0; bb < RR; ++bb)
      acc += att[r * RR + bb] * basis[((size_t)bb * ic + k) * oc + o];
    val = a[r] * acc;
  } else {
    val = root[(size_t)k * oc + o];
  }
  Wt[(size_t)o * cols + col] = f2b(val);
}

// ---------------- aggregation (segment sums + self row) ----------------
// MLP-restructured: all 8 (start,count) pairs hoisted via int4 loads; relations
// processed in concurrent pairs (r, r+4) with x2-unrolled edge loops -> up to
// 4 independent 16B gathers in flight per wave (was ~1).
__global__ __launch_bounds__(256) void aggregate_k(
    const bf16* __restrict__ h, const int* __restrict__ segstart,
    const int* __restrict__ counts, const int* __restrict__ ssrc,
    bf16* __restrict__ agg, int ic, int tpnsh) {
  int tpn = 1 << tpnsh;
  int npb = 256 >> tpnsh;
  int local = threadIdx.x >> tpnsh;
  int n = blockIdx.x * npb + local;
  if (n >= NN) return;
  int cbase = (threadIdx.x & (tpn - 1)) * 8;
  size_t rowoff = (size_t)n * (9 * ic);
  const bf16* hc = h + cbase;

  // hoist all metadata: 4 vector loads, issued up front
  intx4 stv0 = *(const intx4*)(segstart + n * RR);
  intx4 stv1 = *(const intx4*)(segstart + n * RR + 4);
  intx4 ctv0 = *(const intx4*)(counts + n * RR);
  intx4 ctv1 = *(const intx4*)(counts + n * RR + 4);
  int sts[8] = {stv0[0], stv0[1], stv0[2], stv0[3], stv1[0], stv1[1], stv1[2], stv1[3]};
  int cts[8] = {ctv0[0], ctv0[1], ctv0[2], ctv0[3], ctv1[0], ctv1[1], ctv1[2], ctv1[3]};

#pragma unroll
  for (int rp = 0; rp < 4; ++rp) {
    const int stA = sts[rp],     cA = cts[rp];
    const int stB = sts[rp + 4], cB = cts[rp + 4];
    float aA[8] = {0.f, 0.f, 0.f, 0.f, 0.f, 0.f, 0.f, 0.f};
    float aB[8] = {0.f, 0.f, 0.f, 0.f, 0.f, 0.f, 0.f, 0.f};
    int iA = 0, iB = 0;
    // steady state: 4 gathers in flight
    while (iA + 2 <= cA && iB + 2 <= cB) {
      int sA0 = ssrc[stA + iA], sA1 = ssrc[stA + iA + 1];
      int sB0 = ssrc[stB + iB], sB1 = ssrc[stB + iB + 1];
      short8 vA0 = *(const short8*)(hc + (size_t)sA0 * ic);
      short8 vA1 = *(const short8*)(hc + (size_t)sA1 * ic);
      short8 vB0 = *(const short8*)(hc + (size_t)sB0 * ic);
      short8 vB1 = *(const short8*)(hc + (size_t)sB1 * ic);
#pragma unroll
      for (int j = 0; j < 8; ++j) {
        aA[j] += bits2f((unsigned short)vA0[j]) + bits2f((unsigned short)vA1[j]);
        aB[j] += bits2f((unsigned short)vB0[j]) + bits2f((unsigned short)vB1[j]);
      }
      iA += 2; iB += 2;
    }
    // drain A
    for (; iA + 2 <= cA; iA += 2) {
      int s0 = ssrc[stA + iA], s1 = ssrc[stA + iA + 1];
      short8 v0 = *(const short8*)(hc + (size_t)s0 * ic);
      short8 v1 = *(const short8*)(hc + (size_t)s1 * ic);
#pragma unroll
      for (int j = 0; j < 8; ++j)
        aA[j] += bits2f((unsigned short)v0[j]) + bits2f((unsigned short)v1[j]);
    }
    if (iA < cA) {
      int s0 = ssrc[stA + iA];
      short8 v0 = *(const short8*)(hc + (size_t)s0 * ic);
#pragma unroll
      for (int j = 0; j < 8; ++j) aA[j] += bits2f((unsigned short)v0[j]);
    }
    // drain B
    for (; iB + 2 <= cB; iB += 2) {
      int s0 = ssrc[stB + iB], s1 = ssrc[stB + iB + 1];
      short8 v0 = *(const short8*)(hc + (size_t)s0 * ic);
      short8 v1 = *(const short8*)(hc + (size_t)s1 * ic);
#pragma unroll
      for (int j = 0; j < 8; ++j)
        aB[j] += bits2f((unsigned short)v0[j]) + bits2f((unsigned short)v1[j]);
    }
    if (iB < cB) {
      int s0 = ssrc[stB + iB];
      short8 v0 = *(const short8*)(hc + (size_t)s0 * ic);
#pragma unroll
      for (int j = 0; j < 8; ++j) aB[j] += bits2f((unsigned short)v0[j]);
    }
    short8 oA, oB;
#pragma unroll
    for (int j = 0; j < 8; ++j) { oA[j] = f2bits(aA[j]); oB[j] = f2bits(aB[j]); }
    *(short8*)(agg + rowoff + rp * ic + cbase) = oA;
    *(short8*)(agg + rowoff + (rp + 4) * ic + cbase) = oB;
  }
  *(short8*)(agg + rowoff + 8 * ic + cbase) =
      *(const short8*)(h + (size_t)n * ic + cbase);
}

// ---------------- split-N bf16 GEMM, bf16 out (conv layers): 128x64 tile, BK=128 ----------------
// Deep K-step: 32 MFMA/wave per iteration with only 2 barriers. As[128][128]+
// Ws[64][128] = 48 KB LDS. Staging: linear LDS dest + inverse-swizzled global
// source; reads via idx128. Output pre-LN conv values in bf16 (halves CONV
// round-trip; rounding is pre-LN so post-LN error ~0.4% relative).
__global__ __launch_bounds__(256) void gemm_f32_k(
    const bf16* __restrict__ A, const bf16* __restrict__ Wt,
    bf16* __restrict__ Cb, int M, int N, int K, int nb) {
  const int bid = blockIdx.x;
  const int xcd = bid & 7;
  const int slot = bid >> 3;
  const int gidx = slot / nb;
  const int member = slot - gidx * nb;
  const int mb = (M + 127) >> 7;
  const int m = gidx * 8 + xcd;
  if (m >= mb) return;
  const int m0 = m * 128;
  const int n0 = member * 64;

  __shared__ __align__(16) bf16 As[128 * 128];
  __shared__ __align__(16) bf16 Ws[64 * 128];
  const int tid = threadIdx.x;
  const int wave = tid >> 6, lane = tid & 63;
  const int quad = lane >> 4, l16 = lane & 15;
  const int wm = (wave >> 1) * 64, wn = (wave & 1) * 32;
  floatx4 acc[4][2];
#pragma unroll
  for (int i = 0; i < 4; ++i)
#pragma unroll
    for (int j = 0; j < 2; ++j) acc[i][j] = (floatx4){0.f, 0.f, 0.f, 0.f};

  for (int k0 = 0; k0 < K; k0 += 128) {
    // As: 32 KB = 8 chunks/wave of 1 KB (4 rows x 16 slots each)
#pragma unroll
    for (int q = 0; q < 8; ++q) {
      int c0 = (wave * 8 + q) * 1024;
      int r = (c0 >> 8) + (lane >> 4);
      int grow = m0 + r; if (grow >= M) grow = M - 1;
      int s = lane & 15;
      int qg = ((s >> 3) << 3) | ((s & 7) ^ (r & 7));
      async_copy16((char*)As + c0, A + (size_t)grow * K + k0 + qg * 8);
    }
    // Ws: 16 KB = 4 chunks/wave
#pragma unroll
    for (int q = 0; q < 4; ++q) {
      int c0 = (wave * 4 + q) * 1024;
      int r = (c0 >> 8) + (lane >> 4);
      int s = lane & 15;
      int qg = ((s >> 3) << 3) | ((s & 7) ^ (r & 7));
      async_copy16((char*)Ws + c0, Wt + (size_t)(n0 + r) * K + k0 + qg * 8);
    }
    __syncthreads();
#pragma unroll
    for (int kk = 0; kk < 4; ++kk) {
      int qg = kk * 4 + quad;
      short8 b0 = *(const short8*)(Ws + idx128(wn + l16, qg));
      short8 b1 = *(const short8*)(Ws + idx128(wn + 16 + l16, qg));
#pragma unroll
      for (int i = 0; i < 4; ++i) {
        short8 a = *(const short8*)(As + idx128(wm + i * 16 + l16, qg));
        acc[i][0] = __builtin_amdgcn_mfma_f32_16x16x32_bf16(a, b0, acc[i][0], 0, 0, 0);
        acc[i][1] = __builtin_amdgcn_mfma_f32_16x16x32_bf16(a, b1, acc[i][1], 0, 0, 0);
      }
    }
    __syncthreads();
  }
#pragma unroll
  for (int i = 0; i < 4; ++i)
#pragma unroll
    for (int j = 0; j < 2; ++j)
#pragma unroll
      for (int r = 0; r < 4; ++r) {
        int row = m0 + wm + i * 16 + quad * 4 + r;
        int col = n0 + wn + j * 16 + l16;
        if (row < M) Cb[(size_t)row * N + col] = f2b(acc[i][j][r]);
      }
}

// ---------------- plain bf16 GEMM (residuals, ZA): bf16 out, 64x64; grid (N/64, M/64) ----------------
__global__ __launch_bounds__(256) void gemm_plain_k(
    const bf16* __restrict__ A, const bf16* __restrict__ Wt,
    bf16* __restrict__ Cb, int M, int N, int K) {
  __shared__ __align__(16) bf16 As[64 * 64];
  __shared__ __align__(16) bf16 Ws[64 * 64];
  const int m0 = blockIdx.y * 64;
  const int n0 = blockIdx.x * 64;
  const int tid = threadIdx.x;
  const int wave = tid >> 6, lane = tid & 63;
  const int quad = lane >> 4, l16 = lane & 15;
  const int wm = (wave >> 1) * 32, wn = (wave & 1) * 32;
  floatx4 acc00 = {0.f, 0.f, 0.f, 0.f};
  floatx4 acc01 = acc00, acc10 = acc00, acc11 = acc00;

  for (int k0 = 0; k0 < K; k0 += 64) {
#pragma unroll
    for (int q = 0; q < 2; ++q) {
      int c0 = (wave * 2 + q) * 1024;
      int row = (c0 >> 7) + (lane >> 3);
      int grow = m0 + row; if (grow >= M) grow = M - 1;
      int ch = (lane & 7) ^ (row & 7);
      async_copy16((char*)As + c0, A + (size_t)grow * K + k0 + ch * 8);
    }
#pragma unroll
    for (int q = 0; q < 2; ++q) {
      int c0 = (wave * 2 + q) * 1024;
      int row = (c0 >> 7) + (lane >> 3);
      int ch = (lane & 7) ^ (row & 7);
      async_copy16((char*)Ws + c0, Wt + (size_t)(n0 + row) * K + k0 + ch * 8);
    }
    __syncthreads();
#pragma unroll
    for (int kk = 0; kk < 64; kk += 32) {
      int qb = (kk >> 3) + quad;
      short8 a0 = *frag_at(As, wm + l16, qb);
      short8 a1 = *frag_at(As, wm + 16 + l16, qb);
      short8 b0 = *frag_at(Ws, wn + l16, qb);
      short8 b1 = *frag_at(Ws, wn + 16 + l16, qb);
      acc00 = __builtin_amdgcn_mfma_f32_16x16x32_bf16(a0, b0, acc00, 0, 0, 0);
      acc01 = __builtin_amdgcn_mfma_f32_16x16x32_bf16(a0, b1, acc01, 0, 0, 0);
      acc10 = __builtin_amdgcn_mfma_f32_16x16x32_bf16(a1, b0, acc10, 0, 0, 0);
      acc11 = __builtin_amdgcn_mfma_f32_16x16x32_bf16(a1, b1, acc11, 0, 0, 0);
    }
    __syncthreads();
  }
  floatx4 accs[2][2] = {{acc00, acc01}, {acc10, acc11}};
#pragma unroll
  for (int i = 0; i < 2; ++i)
#pragma unroll
    for (int j = 0; j < 2; ++j)
#pragma unroll
      for (int r = 0; r < 4; ++r) {
        int row = m0 + wm + i * 16 + quad * 4 + r;
        int col = n0 + wn + j * 16 + l16;
        if (row < M) Cb[(size_t)row * N + col] = f2b(accs[i][j][r]);
      }
}

// ---------------- LN (+residual, +gelu) for conv layers ----------------
// conv now bf16; short8 vector loads (16B/lane), lpr lanes per row.
__global__ __launch_bounds__(256) void ln_conv_k(
    const bf16* __restrict__ conv, const bf16* __restrict__ res,
    const float* __restrict__ g, const float* __restrict__ b,
    bf16* __restrict__ out, float* __restrict__ zout, int oc, int do_gelu) {
  const int lprsh = (oc == 256) ? 5 : 4;       // lanes per row = oc/8
  const int lpr = 1 << lprsh;
  const int rpb = 256 >> lprsh;
  int row = blockIdx.x * rpb + (threadIdx.x >> lprsh);
  if (row >= NN) return;
  int cb = (threadIdx.x & (lpr - 1)) * 8;
  short8 cv = *(const short8*)(conv + (size_t)row * oc + cb);
  float v[8];
  float s = 0.f, s2 = 0.f;
#pragma unroll
  for (int j = 0; j < 8; ++j) {
    v[j] = bits2f((unsigned short)cv[j]);
    s += v[j]; s2 += v[j] * v[j];
  }
  for (int off = lpr >> 1; off; off >>= 1) { s += __shfl_xor(s, off); s2 += __shfl_xor(s2, off); }
  float m = s / oc;
  float var = s2 / oc - m * m;
  float rs = rsqrtf(var + 1e-5f);
  short8 rv = *(const short8*)(res + (size_t)row * oc + cb);
  short8 ov;
#pragma unroll
  for (int j = 0; j < 8; ++j) {
    int c = cb + j;
    float y = (v[j] - m) * rs * g[c] + b[c];
    y += bits2f((unsigned short)rv[j]);
    if (zout) zout[(size_t)row * oc + c] = y;
    if (do_gelu) y = gelu_f(y);
    ov[j] = f2bits(y);
  }
  *(short8*)(out + (size_t)row * oc + cb) = ov;
}

// ---------------- decoder GEMM0 (nb=2, combined-K, XCD-pinned) ----------------
// P0[128 pairs][128 cols] per block; K=256 = prod128|diff128 via WPE.
__global__ __launch_bounds__(256) void gemm_pe_k(
    const bf16* __restrict__ z, const int* __restrict__ pairs,
    const bf16* __restrict__ WPE,  // [256 out][256 K]  (K = prod128 | diff128)
    bf16* __restrict__ P0) {
  const int bid = blockIdx.x;
  const int xcd = bid & 7;
  const int slot = bid >> 3;
  const int gidx = slot >> 1;          // nb = 2
  const int member = slot & 1;
  const int mb = (PP + 127) >> 7;
  const int m = gidx * 8 + xcd;
  if (m >= mb) return;
  const int m0 = m * 128;
  const int n0 = member * 128;

  __shared__ __align__(16) bf16 PEs[128 * 128];  // A tile: localk = prod64|diff64 of kwi
  __shared__ __align__(16) bf16 Ws[128 * 128];   // B tile: 128 cols x same localk
  const int tid = threadIdx.x;
  const int wave = tid >> 6, lane = tid & 63;
  const int quad = lane >> 4, l16 = lane & 15;
  const int wm = (wave >> 1) * 64, wn = (wave & 1) * 64;

  const int prow = tid >> 1;           // 0..127
  const int h = tid & 1;               // 32-col half of the 64-col z chunk
  int pp = m0 + prow; if (pp >= PP) pp = PP - 1;
  const bf16* zi = z + (size_t)pairs[pp] * 128;
  const bf16* zj = z + (size_t)pairs[PP + pp] * 128;

  floatx4 acc[4][4];
#pragma unroll
  for (int i = 0; i < 4; ++i)
#pragma unroll
    for (int j = 0; j < 4; ++j) acc[i][j] = (floatx4){0.f, 0.f, 0.f, 0.f};

#pragma unroll
  for (int kwi = 0; kwi < 2; ++kwi) {
    const int kw = kwi * 64;
    // z slice loads issued before the entry barrier (overlap the wait)
    short8 va[4], vb[4];
#pragma unroll
    for (int c8 = 0; c8 < 4; ++c8) {
      va[c8] = *(const short8*)(zi + kw + h * 32 + c8 * 8);
      vb[c8] = *(const short8*)(zj + kw + h * 32 + c8 * 8);
    }
    if (kwi) __syncthreads();          // waves done reading PEs/Ws of prev phase
    // stage Ws[128][128] via async: pre-swizzled global source, linear LDS dest.
#pragma unroll
    for (int q = 0; q < 8; ++q) {
      int c0 = (wave * 8 + q) * 1024;              // byte offset (1KB = 4 rows)
      int r = (c0 >> 8) + (lane >> 4);
      int s = lane & 15;
      async_copy16((char*)Ws + c0,
                   WPE + (size_t)(n0 + r) * 256 + ((s >> 3) << 7) + kw + (((s & 7) ^ (r & 7)) << 3));
    }
    // build PEs: localk 0..63 = prod, 64..127 = absdiff (both ops, one pass)
#pragma unroll
    for (int c8 = 0; c8 < 4; ++c8) {
      short8 op, od;
#pragma unroll
      for (int jj = 0; jj < 8; ++jj) {
        float fa = bits2f((unsigned short)va[c8][jj]);
        float fb = bits2f((unsigned short)vb[c8][jj]);
        op[jj] = f2bits(fa * fb);
        od[jj] = f2bits(fabsf(fa - fb));
      }
      *(short8*)(PEs + idx128(prow, h * 4 + c8)) = op;
      *(short8*)(PEs + idx128(prow, 8 + h * 4 + c8)) = od;
    }
    __syncthreads();                   // drains async vmcnt + PE writes
    // MFMA over localk=128 (4 slices of 32)
#pragma unroll
    for (int ks = 0; ks < 4; ++ks) {
      const int qg = ks * 4 + quad;
      short8 bfr[4];
#pragma unroll
      for (int j = 0; j < 4; ++j)
        bfr[j] = *(const short8*)(Ws + idx128(wn + j * 16 + l16, qg));
#pragma unroll
      for (int i = 0; i < 4; ++i) {
        short8 a = *(const short8*)(PEs + idx128(wm + i * 16 + l16, qg));
#pragma unroll
        for (int j = 0; j < 4; ++j)
          acc[i][j] = __builtin_amdgcn_mfma_f32_16x16x32_bf16(a, bfr[j], acc[i][j], 0, 0, 0);
      }
    }
  }

#pragma unroll
  for (int i = 0; i < 4; ++i)
#pragma unroll
    for (int j = 0; j < 4; ++j)
#pragma unroll
      for (int r = 0; r < 4; ++r) {
        int row = m0 + wm + i * 16 + quad * 4 + r;
        int col = n0 + wn + j * 16 + l16;
        if (row < PP) P0[(size_t)row * 256 + col] = f2b(acc[i][j][r]);
      }
}

// ---------------- elementwise: D0 = gelu(ln(P0 + ZA[gi] + ZA[gj] + db0)) in place ----------------
__global__ __launch_bounds__(256) void ln_d0_k(bf16* __restrict__ D0,
                                               const int* __restrict__ pairs,
                                               const bf16* __restrict__ ZA,
                                               const float* __restrict__ db0,
                                               const float* __restrict__ g,
                                               const float* __restrict__ b) {
  const int wave = threadIdx.x >> 6, lane = threadIdx.x & 63;
  const int row = blockIdx.x * 8 + wave * 2 + (lane >> 5);   // PP % 8 == 0
  const int cb = (lane & 31) * 8;
  int gi = pairs[row], gj = pairs[PP + row];
  bf16* p = D0 + (size_t)row * 256 + cb;
  short8 xv = *(const short8*)p;
  short8 av = *(const short8*)(ZA + (size_t)gi * 256 + cb);
  short8 bv = *(const short8*)(ZA + (size_t)gj * 256 + cb);
  float v[8];
  float s = 0.f, s2 = 0.f;
#pragma unroll
  for (int k = 0; k < 8; ++k) {
    v[k] = bits2f((unsigned short)xv[k]) + bits2f((unsigned short)av[k]) +
           bits2f((unsigned short)bv[k]) + db0[cb + k];
    s += v[k]; s2 += v[k] * v[k];
  }
  // reduce within each 32-lane half (one row per half)
  for (int off = 16; off; off >>= 1) { s += __shfl_xor(s, off); s2 += __shfl_xor(s2, off); }
  float m = s / 256.f;
  float var = s2 / 256.f - m * m;
  float rs = rsqrtf(var + 1e-5f);
  short8 ov;
#pragma unroll
  for (int k = 0; k < 8; ++k) {
    float y = (v[k] - m) * rs * g[cb + k] + b[cb + k];
    ov[k] = f2bits(gelu_f(y));
  }
  *(short8*)p = ov;
}

// ---------------- decoder GEMM1: A = D0 (bf16) staged; P1 = A@W1^T + db1 ----------------
__global__ __launch_bounds__(256) void lngemm1_k(
    const bf16* __restrict__ D0, const bf16* __restrict__ W1t,  // [128][256]
    const float* __restrict__ bias, bf16* __restrict__ P1, int M) {
  __shared__ __align__(16) bf16 As[64 * 256];
  __shared__ __align__(16) bf16 Ws[128 * 64];
  const int tid = threadIdx.x;
  const int wave = tid >> 6, lane = tid & 63;
  const int quad = lane >> 4, l16 = lane & 15;
  const int wr = (wave >> 1) * 32;
  const int wc = (wave & 1) * 64;
  const int m0 = blockIdx.x * 64;

  // stage A (already post-LN/GELU bf16)
  {
    const int srow = tid >> 2;
    const int q4 = tid & 3;
    int grow = m0 + srow; if (grow >= M) grow = M - 1;
    const bf16* src = D0 + (size_t)grow * 256 + q4 * 64;
#pragma unroll
    for (int c8 = 0; c8 < 8; ++c8) {
      short8 o = *(const short8*)(src + c8 * 8);
      *(short8*)(As + srow * 256 + q4 * 64 + ((c8 ^ (srow & 7)) << 3)) = o;
    }
  }

  floatx4 acc[2][4];
#pragma unroll
  for (int i = 0; i < 2; ++i)
#pragma unroll
    for (int j = 0; j < 4; ++j) acc[i][j] = (floatx4){0.f, 0.f, 0.f, 0.f};

  for (int kc = 0; kc < 4; ++kc) {
#pragma unroll
    for (int q = 0; q < 4; ++q) {
      int c0 = q * 4096 + wave * 1024;
      int row = (c0 >> 7) + (lane >> 3);
      int ch = (lane & 7) ^ (row & 7);
      async_copy16((char*)Ws + c0, W1t + (size_t)row * 256 + kc * 64 + ch * 8);
    }
    __syncthreads();
#pragma unroll
    for (int kk = 0; kk < 64; kk += 32) {
      int qb = (kk >> 3) + quad;
      short8 a0 = *frag256(As, wr + l16, kc * 64, qb);
      short8 a1 = *frag256(As, wr + 16 + l16, kc * 64, qb);
#pragma unroll
      for (int j = 0; j < 4; ++j) {
        short8 bb = *frag_at(Ws, wc + j * 16 + l16, qb);
        acc[0][j] = __builtin_amdgcn_mfma_f32_16x16x32_bf16(a0, bb, acc[0][j], 0, 0, 0);
        acc[1][j] = __builtin_amdgcn_mfma_f32_16x16x32_bf16(a1, bb, acc[1][j], 0, 0, 0);
      }
    }
    __syncthreads();
  }

#pragma unroll
  for (int i = 0; i < 2; ++i)
#pragma unroll
    for (int r = 0; r < 4; ++r) {
      int row = wr + i * 16 + quad * 4 + r;
      int grow = m0 + row;
      if (grow >= M) continue;
#pragma unroll
      for (int j = 0; j < 4; ++j) {
        int col = wc + j * 16 + l16;
        P1[(size_t)grow * 128 + col] = f2b(acc[i][j][r] + bias[col]);
      }
    }
}

// ---------------- decoder GEMM2 + logits (fused): A = gelu(ln(P1));
// t = gelu(ln(A@W2^T + db2)) . w3 + b3  -> out[p].  LN(64) + dot done
// in-register via shfl within each 16-lane quad group. ----------------
__global__ __launch_bounds__(256) void lngemm2_k(
    const bf16* __restrict__ P1, const bf16* __restrict__ W2t,  // [64][128]
    const float* __restrict__ g, const float* __restrict__ b,
    const float* __restrict__ bias,
    const float* __restrict__ g2, const float* __restrict__ b2,
    const float* __restrict__ w3, const float* __restrict__ b3,
    float* __restrict__ out, int M) {
  __shared__ __align__(16) bf16 As[64 * 128];
  __shared__ __align__(16) bf16 Ws[64 * 64];
  const int tid = threadIdx.x;
  const int wave = tid >> 6, lane = tid & 63;
  const int quad = lane >> 4, l16 = lane & 15;
  const int m0 = blockIdx.x * 64;

  {
    const int srow = tid >> 2;
    const int q4 = tid & 3;
    int grow = m0 + srow; if (grow >= M) grow = M - 1;
    const bf16* src = P1 + (size_t)grow * 128 + q4 * 32;
    float v[32];
    float s = 0.f, s2 = 0.f;
#pragma unroll
    for (int c8 = 0; c8 < 4; ++c8) {
      short8 x = *(const short8*)(src + c8 * 8);
#pragma unroll
      for (int jj = 0; jj < 8; ++jj) {
        float f = bits2f((unsigned short)x[jj]);
        v[c8 * 8 + jj] = f; s += f; s2 += f * f;
      }
    }
    s += __shfl_xor(s, 1); s2 += __shfl_xor(s2, 1);
    s += __shfl_xor(s, 2); s2 += __shfl_xor(s2, 2);
    float mean = s / 128.f;
    float var = s2 / 128.f - mean * mean;
    float rs = rsqrtf(var + 1e-5f);
#pragma unroll
    for (int c8 = 0; c8 < 4; ++c8) {
      short8 o;
#pragma unroll
      for (int jj = 0; jj < 8; ++jj) {
        int col = q4 * 32 + c8 * 8 + jj;
        float y = (v[c8 * 8 + jj] - mean) * rs * g[col] + b[col];
        o[jj] = f2bits(gelu_f(y));
      }
      *(short8*)(As + idx128(srow, q4 * 4 + c8)) = o;
    }
  }

  floatx4 acc[4];
#pragma unroll
  for (int j = 0; j < 4; ++j) acc[j] = (floatx4){0.f, 0.f, 0.f, 0.f};

  for (int kc = 0; kc < 2; ++kc) {
#pragma unroll
    for (int q = 0; q < 2; ++q) {
      int c0 = q * 4096 + wave * 1024;
      int row = (c0 >> 7) + (lane >> 3);
      int ch = (lane & 7) ^ (row & 7);
      async_copy16((char*)Ws + c0, W2t + (size_t)row * 128 + kc * 64 + ch * 8);
    }
    __syncthreads();
#pragma unroll
    for (int kk = 0; kk < 64; kk += 32) {
      int qb = (kk >> 3) + quad;
      short8 a = *(const short8*)(As + idx128(wave * 16 + l16, kc * 8 + qb));
#pragma unroll
      for (int j = 0; j < 4; ++j) {
        short8 bb = *frag_at(Ws, j * 16 + l16, qb);
        acc[j] = __builtin_amdgcn_mfma_f32_16x16x32_bf16(a, bb, acc[j], 0, 0, 0);
      }
    }
    __syncthreads();
  }

  // fused epilogue: per row (owned by 16 contiguous lanes of this quad group):
  // y = acc + db2; LN over 64; gelu; dot with w3; write out[row].
#pragma unroll
  for (int r = 0; r < 4; ++r) {
    int row = wave * 16 + quad * 4 + r;
    int grow = m0 + row;
    float y[4];
    float s = 0.f, s2 = 0.f;
#pragma unroll
    for (int j = 0; j < 4; ++j) {
      int col = j * 16 + l16;
      y[j] = acc[j][r] + bias[col];
      s += y[j]; s2 += y[j] * y[j];
    }
    for (int off = 8; off; off >>= 1) { s += __shfl_xor(s, off); s2 += __shfl_xor(s2, off); }
    float mean = s / 64.f;
    float var = s2 / 64.f - mean * mean;
    float rs = rsqrtf(var + 1e-5f);
    float t = 0.f;
#pragma unroll
    for (int j = 0; j < 4; ++j) {
      int col = j * 16 + l16;
      float yy = gelu_f((y[j] - mean) * rs * g2[col] + b2[col]);
      t += yy * w3[col];
    }
    for (int off = 8; off; off >>= 1) t += __shfl_xor(t, off);
    if (l16 == 0 && grow < M) out[grow] = t + b3[0];
  }
}

// ---------------- host ----------------
extern "C" void kernel_launch(void* const* d_in, const int* in_sizes, int n_in,
                              void* d_out, int out_size, void* d_ws, size_t ws_size,
                              hipStream_t stream) {
  auto cdiv = [](int a, int b) { return (a + b - 1) / b; };

  const float* x = (const float*)d_in[0];
  const int* ei = (const int*)d_in[1];
  const int* et = (const int*)d_in[2];
  const int* gp = (const int*)d_in[3];
  const float *basis[4], *att[4], *root[4], *relatt[4], *gln[4], *bln[4];
  for (int l = 0; l < 4; ++l) {
    basis[l]  = (const float*)d_in[4 + 6 * l];
    att[l]    = (const float*)d_in[5 + 6 * l];
    root[l]   = (const float*)d_in[6 + 6 * l];
    relatt[l] = (const float*)d_in[7 + 6 * l];
    gln[l]    = (const float*)d_in[8 + 6 * l];
    bln[l]    = (const float*)d_in[9 + 6 * l];
  }
  const float* res0 = (const float*)d_in[28];
  const float* res3 = (const float*)d_in[29];
  const float* dW0 = (const float*)d_in[30]; const float* db0 = (const float*)d_in[31];
  const float* dg0 = (const float*)d_in[32]; const float* dbb0 = (const float*)d_in[33];
  const float* dW1 = (const float*)d_in[34]; const float* db1 = (const float*)d_in[35];
  const float* dg1 = (const float*)d_in[36]; const float* dbb1 = (const float*)d_in[37];
  const float* dW2 = (const float*)d_in[38]; const float* db2 = (const float*)d_in[39];
  const float* dg2 = (const float*)d_in[40]; const float* dbb2 = (const float*)d_in[41];
  const float* dW3 = (const float*)d_in[42]; const float* db3 = (const float*)d_in[43];

  char* base = (char*)d_ws;
  size_t off = 0;
  auto alloc = [&](size_t bytes) -> char* {
    char* p = base + off;
    off += (bytes + 255) & ~(size_t)255;
    return p;
  };
  bf16* X16 = (bf16*)alloc((size_t)NN * 128 * 2);
  bf16* HA  = (bf16*)alloc((size_t)NN * 256 * 2);
  bf16* HB  = (bf16*)alloc((size_t)NN * 256 * 2);
  bf16* RESB = (bf16*)alloc((size_t)NN * 256 * 2);
  bf16* ZA   = (bf16*)alloc((size_t)NN * 256 * 2);
  bf16* CONV = (bf16*)alloc((size_t)NN * 256 * 2);
  bf16* WT    = (bf16*)alloc((size_t)589824 * 2);
  bf16* RES0T = (bf16*)alloc((size_t)32768 * 2);
  bf16* RES3T = (bf16*)alloc((size_t)32768 * 2);
  bf16* WAT   = (bf16*)alloc((size_t)32768 * 2);
  bf16* WPE   = (bf16*)alloc((size_t)65536 * 2);   // [256][256] combined prod|diff W^T
  bf16* DW1T  = (bf16*)alloc((size_t)32768 * 2);
  bf16* DW2T  = (bf16*)alloc((size_t)8192 * 2);
  float* ASOFT = (float*)alloc(32 * 4);
  int* COUNTS = (int*)alloc((size_t)NR * 4);
  int* SEG    = (int*)alloc((size_t)NR * 4);
  int* CUR    = (int*)alloc((size_t)NR * 4);
  int* BS     = (int*)alloc(1024 * 4);
  int* SSRC   = (int*)alloc((size_t)EE * 4);
  char* BIG = alloc(93000000);   // overlay: AGG [N,2304]bf16 (92.2MB) | P0/D0 [P,256]bf16 (51.2MB)
  bf16* AGG = (bf16*)BIG;
  bf16* P0  = (bf16*)BIG;
  bf16* P1  = (bf16*)alloc((size_t)PP * 128 * 2);
  (void)ws_size; (void)in_sizes; (void)n_in; (void)out_size;

  float* out_logits = (float*)d_out;
  float* out_z = (float*)d_out + PP;

  // --- CSR build ---
  hipMemsetAsync(COUNTS, 0, (size_t)NR * 4, stream);
  hipMemsetAsync(CUR, 0, (size_t)NR * 4, stream);
  hist_k<<<cdiv(EE, 256), 256, 0, stream>>>(ei + EE, et, COUNTS);
  scan1_k<<<NR / 256, 256, 0, stream>>>(COUNTS, SEG, BS);
  scan2_k<<<1, 256, 0, stream>>>(BS, NR / 256);
  scan3_k<<<NR / 256, 256, 0, stream>>>(SEG, BS);
  scatter_k<<<cdiv(EE, 256), 256, 0, stream>>>(ei, ei + EE, et, SEG, CUR, SSRC);

  // --- weight prep ---
  cvt_bf16_k<<<cdiv(NN * 128, 256), 256, 0, stream>>>(x, X16, NN * 128);
  softmax4_k<<<1, 64, 0, stream>>>(relatt[0], relatt[1], relatt[2], relatt[3], ASOFT);
  prep_small_k<<<cdiv(172032, 256), 256, 0, stream>>>(res0, res3, dW0, dW1, dW2,
                                                      RES0T, RES3T, WAT, WPE, DW1T, DW2T);

  const int mb = cdiv(NN, 128);            // 157
  const int swzP4 = 8 * cdiv(mb, 8) * 4;   // nb=4
  const int swzP2 = 8 * cdiv(mb, 8) * 2;   // nb=2

  // --- layer 0: ic=128, oc=256, residual = x @ res0 ---
  prep_w_k<<<cdiv(9 * 128 * 256, 256), 256, 0, stream>>>(basis[0], att[0], root[0], ASOFT + 0, WT, 128, 7, 256, 8);
  aggregate_k<<<cdiv(NN, 16), 256, 0, stream>>>(X16, SEG, COUNTS, SSRC, AGG, 128, 4);
  gemm_plain_k<<<dim3(4, cdiv(NN, 64)), 256, 0, stream>>>(X16, RES0T, RESB, NN, 256, 128);
  gemm_f32_k<<<swzP4, 256, 0, stream>>>(AGG, WT, CONV, NN, 256, 1152, 4);
  ln_conv_k<<<cdiv(NN, 8), 256, 0, stream>>>(CONV, RESB, gln[0], bln[0], HA, nullptr, 256, 1);

  // --- layer 1 ---
  prep_w_k<<<cdiv(9 * 256 * 256, 256), 256, 0, stream>>>(basis[1], att[1], root[1], ASOFT + 8, WT, 256, 8, 256, 8);
  aggregate_k<<<cdiv(NN, 8), 256, 0, stream>>>(HA, SEG, COUNTS, SSRC, AGG, 256, 5);
  gemm_f32_k<<<swzP4, 256, 0, stream>>>(AGG, WT, CONV, NN, 256, 2304, 4);
  ln_conv_k<<<cdiv(NN, 8), 256, 0, stream>>>(CONV, HA, gln[1], bln[1], HB, nullptr, 256, 1);

  // --- layer 2 ---
  prep_w_k<<<cdiv(9 * 256 * 256, 256), 256, 0, stream>>>(basis[2], att[2], root[2], ASOFT + 16, WT, 256, 8, 256, 8);
  aggregate_k<<<cdiv(NN, 8), 256, 0, stream>>>(HB, SEG, COUNTS, SSRC, AGG, 256, 5);
  gemm_f32_k<<<swzP4, 256, 0, stream>>>(AGG, WT, CONV, NN, 256, 2304, 4);
  ln_conv_k<<<cdiv(NN, 8), 256, 0, stream>>>(CONV, HB, gln[2], bln[2], HA, nullptr, 256, 1);

  // --- layer 3: oc=128, residual = h_in @ res3, no gelu; writes z (fp32 out_z) + HB ---
  prep_w_k<<<cdiv(9 * 256 * 128, 256), 256, 0, stream>>>(basis[3], att[3], root[3], ASOFT + 24, WT, 256, 8, 128, 7);
  aggregate_k<<<cdiv(NN, 8), 256, 0, stream>>>(HA, SEG, COUNTS, SSRC, AGG, 256, 5);
  gemm_plain_k<<<dim3(2, cdiv(NN, 64)), 256, 0, stream>>>(HA, RES3T, RESB, NN, 128, 256);
  gemm_f32_k<<<swzP2, 256, 0, stream>>>(AGG, WT, CONV, NN, 128, 2304, 2);
  ln_conv_k<<<cdiv(NN, 16), 256, 0, stream>>>(CONV, RESB, gln[3], bln[3], HB, out_z, 128, 0);

  // --- decoder ---
  gemm_plain_k<<<dim3(4, cdiv(NN, 64)), 256, 0, stream>>>(HB, WAT, ZA, NN, 256, 128);
  const int pb = cdiv(PP, 128);            // 782
  const int swzPE = 8 * cdiv(pb, 8) * 2;   // nb=2
  gemm_pe_k<<<swzPE, 256, 0, stream>>>(HB, gp, WPE, P0);
  ln_d0_k<<<cdiv(PP, 8), 256, 0, stream>>>(P0, gp, ZA, db0, dg0, dbb0);
  lngemm1_k<<<cdiv(PP, 64), 256, 0, stream>>>(P0, DW1T, db1, P1, PP);
  lngemm2_k<<<cdiv(PP, 64), 256, 0, stream>>>(P1, DW2T, dg1, dbb1, db2, dg2, dbb2,
                                              dW3, db3, out_logits, PP);
}

// Round 10
// 690.210 us; speedup vs baseline: 1.0084x; 1.0084x over previous
//
#include <hip/hip_runtime.h>
#include <hip/hip_bf16.h>
#include <math.h>
#include <cstddef>
#include <stdint.h>

#define NN 20000
#define EE 320000
#define RR 8
#define PP 100000
#define NR (NN * RR)   // 160000 = 625*256

typedef __hip_bfloat16 bf16;
typedef __attribute__((ext_vector_type(8))) short short8;
typedef __attribute__((ext_vector_type(4))) short short4v;
typedef __attribute__((ext_vector_type(4))) float floatx4;
typedef __attribute__((ext_vector_type(4))) int intx4;

__device__ __forceinline__ float b2f(bf16 v) { return __bfloat162float(v); }
__device__ __forceinline__ bf16 f2b(float v) { return __float2bfloat16(v); }
__device__ __forceinline__ float bits2f(unsigned short u) {
  unsigned int i = ((unsigned int)u) << 16; float f; __builtin_memcpy(&f, &i, 4); return f;
}
__device__ __forceinline__ short f2bits(float f) {
  bf16 h = __float2bfloat16(f); short s; __builtin_memcpy(&s, &h, 2); return s;
}
// fast tanh-form gelu: x*sigmoid(2t), t = 0.79788456*(x + 0.044715*x^3).
// 0.5*(1+tanh(t)) == 1/(1+e^{-2t}) == rcp(1 + 2^{-2.885390082*t}).
// max |delta| vs exact-erf gelu ~3e-4 << bf16 quantization noise.
__device__ __forceinline__ float gelu_f(float x) {
  float t = x * (0.7978845608f + 0.0356774081f * x * x);
  float s = exp2f(-2.885390082f * t);
  return x * __builtin_amdgcn_rcpf(1.f + s);
}
// async global->LDS, 16B per lane; lds base wave-uniform, lane i lands at base+i*16
__device__ __forceinline__ void async_copy16(void* lds, const void* g) {
  __builtin_amdgcn_global_load_lds((const __attribute__((address_space(1))) void*)g,
                                   (__attribute__((address_space(3))) void*)lds, 16, 0, 0);
}
// swizzled fragment address, [rows][64] bf16 tile (stride 64): chunk q lives at q^(row&7)
__device__ __forceinline__ const short8* frag_at(const bf16* base, int row, int q) {
  return (const short8*)(base + row * 64 + (((q) ^ (row & 7)) << 3));
}
// stride-256 variant (col64 = 64-col group base), and stride-128 variant (qg = global chunk)
__device__ __forceinline__ const short8* frag256(const bf16* base, int row, int col64, int q) {
  return (const short8*)(base + row * 256 + col64 + (((q) ^ (row & 7)) << 3));
}
__device__ __forceinline__ int idx128(int row, int qg) {
  return row * 128 + ((qg >> 3) << 6) + (((qg & 7) ^ (row & 7)) << 3);
}

// ---------------- CSR build ----------------
__global__ void hist_k(const int* __restrict__ dst, const int* __restrict__ et,
                       int* __restrict__ counts) {
  int e = blockIdx.x * 256 + threadIdx.x;
  if (e >= EE) return;
  atomicAdd(&counts[dst[e] * RR + et[e]], 1);
}

__global__ void scan1_k(const int* __restrict__ counts, int* __restrict__ prefix,
                        int* __restrict__ bsums) {
  __shared__ int tmp[256];
  int i = blockIdx.x * 256 + threadIdx.x;
  int v = counts[i];
  tmp[threadIdx.x] = v; __syncthreads();
  for (int off = 1; off < 256; off <<= 1) {
    int x = (threadIdx.x >= off) ? tmp[threadIdx.x - off] : 0;
    __syncthreads();
    tmp[threadIdx.x] += x;
    __syncthreads();
  }
  prefix[i] = tmp[threadIdx.x] - v;
  if (threadIdx.x == 255) bsums[blockIdx.x] = tmp[255];
}

__global__ void scan2_k(int* __restrict__ bsums, int nb) {
  __shared__ int tmp[256];
  __shared__ int carry;
  if (threadIdx.x == 0) carry = 0;
  __syncthreads();
  for (int base = 0; base < nb; base += 256) {
    int i = base + threadIdx.x;
    int v = (i < nb) ? bsums[i] : 0;
    tmp[threadIdx.x] = v; __syncthreads();
    for (int off = 1; off < 256; off <<= 1) {
      int x = (threadIdx.x >= off) ? tmp[threadIdx.x - off] : 0;
      __syncthreads();
      tmp[threadIdx.x] += x;
      __syncthreads();
    }
    int c = carry;
    if (i < nb) bsums[i] = c + tmp[threadIdx.x] - v;
    __syncthreads();
    if (threadIdx.x == 255) carry = c + tmp[255];
    __syncthreads();
  }
}

__global__ void scan3_k(int* __restrict__ prefix, const int* __restrict__ bsums) {
  int i = blockIdx.x * 256 + threadIdx.x;
  prefix[i] += bsums[blockIdx.x];
}

__global__ void scatter_k(const int* __restrict__ src, const int* __restrict__ dst,
                          const int* __restrict__ et, const int* __restrict__ segstart,
                          int* __restrict__ cursor, int* __restrict__ ssrc) {
  int e = blockIdx.x * 256 + threadIdx.x;
  if (e >= EE) return;
  int s = dst[e] * RR + et[e];
  int pos = atomicAdd(&cursor[s], 1);
  ssrc[segstart[s] + pos] = src[e];
}

// ---------------- small prep kernels ----------------
__global__ void cvt_bf16_k(const float* __restrict__ in, bf16* __restrict__ out, int n) {
  int i = blockIdx.x * 256 + threadIdx.x;
  if (i < n) out[i] = f2b(in[i]);
}

__global__ void softmax4_k(const float* r0, const float* r1, const float* r2,
                           const float* r3, float* __restrict__ a) {
  if (threadIdx.x == 0) {
    const float* rs[4] = {r0, r1, r2, r3};
    for (int l = 0; l < 4; ++l) {
      float mx = -1e30f;
      for (int i = 0; i < RR; ++i) mx = fmaxf(mx, rs[l][i]);
      float e[RR]; float s = 0.f;
      for (int i = 0; i < RR; ++i) { e[i] = expf(rs[l][i] - mx); s += e[i]; }
      for (int i = 0; i < RR; ++i) a[l * RR + i] = e[i] / s;
    }
  }
}

// all small weight transposes batched into ONE launch (was 6 launches)
__global__ void prep_small_k(const float* __restrict__ res0, const float* __restrict__ res3,
                             const float* __restrict__ dW0, const float* __restrict__ dW1,
                             const float* __restrict__ dW2,
                             bf16* __restrict__ RES0T, bf16* __restrict__ RES3T,
                             bf16* __restrict__ WAT, bf16* __restrict__ WPE,
                             bf16* __restrict__ DW1T, bf16* __restrict__ DW2T) {
  int idx = blockIdx.x * 256 + threadIdx.x;
  if (idx < 32768) {                         // res0 [128][256] -> T
    int r = idx >> 8, c = idx & 255;
    RES0T[(size_t)c * 128 + r] = f2b(res0[idx]);
  } else if (idx < 65536) {                  // res3 [256][128] -> T
    int i2 = idx - 32768; int r = i2 >> 7, c = i2 & 127;
    RES3T[(size_t)c * 256 + r] = f2b(res3[i2]);
  } else if (idx < 98304) {                  // WA = dW0[0:128] [128][256] -> T
    int i2 = idx - 65536; int r = i2 >> 8, c = i2 & 255;
    WAT[(size_t)c * 128 + r] = f2b(dW0[i2]);
  } else if (idx < 131072) {                 // WPE: prod|diff combined K
    int i2 = idx - 98304; int k = i2 >> 8, o = i2 & 255;
    WPE[(size_t)o * 256 + k] = f2b(dW0[128 * 256 + i2]);
    WPE[(size_t)o * 256 + 128 + k] = f2b(dW0[256 * 256 + i2]);
  } else if (idx < 163840) {                 // dW1 [256][128] -> T
    int i2 = idx - 131072; int r = i2 >> 7, c = i2 & 127;
    DW1T[(size_t)c * 256 + r] = f2b(dW1[i2]);
  } else if (idx < 172032) {                 // dW2 [128][64] -> T
    int i2 = idx - 163840; int r = i2 >> 6, c = i2 & 63;
    DW2T[(size_t)c * 128 + r] = f2b(dW2[i2]);
  }
}

// coalesced: consecutive threads -> consecutive o -> basis reads coalesced
__global__ void prep_w_k(const float* __restrict__ basis, const float* __restrict__ att,
                         const float* __restrict__ root, const float* __restrict__ a,
                         bf16* __restrict__ Wt, int ic, int icsh, int oc, int ocsh) {
  int idx = blockIdx.x * 256 + threadIdx.x;
  int cols = 9 * ic;
  if (idx >= cols * oc) return;
  int o = idx & (oc - 1);
  int col = idx >> ocsh;
  int r = col >> icsh;
  int k = col & (ic - 1);
  float val;
  if (r < RR) {
    float acc = 0.f;
    for (int bb = 0; bb < RR; ++bb)
      acc += att[r * RR + bb] * basis[((size_t)bb * ic + k) * oc + o];
    val = a[r] * acc;
  } else {
    val = root[(size_t)k * oc + o];
  }
  Wt[(size_t)o * cols + col] = f2b(val);
}

// ---------------- aggregation (segment sums; self row NOT materialized) ----------------
// AGG stride = 8*ic (self/root A-operand is read straight from h in the GEMM).
// MLP-restructured: all 8 (start,count) pairs hoisted via int4 loads; relations
// processed in concurrent pairs (r, r+4) with x2-unrolled edge loops -> up to
// 4 independent 16B gathers in flight per wave.
__global__ __launch_bounds__(256) void aggregate_k(
    const bf16* __restrict__ h, const int* __restrict__ segstart,
    const int* __restrict__ counts, const int* __restrict__ ssrc,
    bf16* __restrict__ agg, int ic, int tpnsh) {
  int tpn = 1 << tpnsh;
  int npb = 256 >> tpnsh;
  int local = threadIdx.x >> tpnsh;
  int n = blockIdx.x * npb + local;
  if (n >= NN) return;
  int cbase = (threadIdx.x & (tpn - 1)) * 8;
  size_t rowoff = (size_t)n * (8 * ic);
  const bf16* hc = h + cbase;

  // hoist all metadata: 4 vector loads, issued up front
  intx4 stv0 = *(const intx4*)(segstart + n * RR);
  intx4 stv1 = *(const intx4*)(segstart + n * RR + 4);
  intx4 ctv0 = *(const intx4*)(counts + n * RR);
  intx4 ctv1 = *(const intx4*)(counts + n * RR + 4);
  int sts[8] = {stv0[0], stv0[1], stv0[2], stv0[3], stv1[0], stv1[1], stv1[2], stv1[3]};
  int cts[8] = {ctv0[0], ctv0[1], ctv0[2], ctv0[3], ctv1[0], ctv1[1], ctv1[2], ctv1[3]};

#pragma unroll
  for (int rp = 0; rp < 4; ++rp) {
    const int stA = sts[rp],     cA = cts[rp];
    const int stB = sts[rp + 4], cB = cts[rp + 4];
    float aA[8] = {0.f, 0.f, 0.f, 0.f, 0.f, 0.f, 0.f, 0.f};
    float aB[8] = {0.f, 0.f, 0.f, 0.f, 0.f, 0.f, 0.f, 0.f};
    int iA = 0, iB = 0;
    // steady state: 4 gathers in flight
    while (iA + 2 <= cA && iB + 2 <= cB) {
      int sA0 = ssrc[stA + iA], sA1 = ssrc[stA + iA + 1];
      int sB0 = ssrc[stB + iB], sB1 = ssrc[stB + iB + 1];
      short8 vA0 = *(const short8*)(hc + (size_t)sA0 * ic);
      short8 vA1 = *(const short8*)(hc + (size_t)sA1 * ic);
      short8 vB0 = *(const short8*)(hc + (size_t)sB0 * ic);
      short8 vB1 = *(const short8*)(hc + (size_t)sB1 * ic);
#pragma unroll
      for (int j = 0; j < 8; ++j) {
        aA[j] += bits2f((unsigned short)vA0[j]) + bits2f((unsigned short)vA1[j]);
        aB[j] += bits2f((unsigned short)vB0[j]) + bits2f((unsigned short)vB1[j]);
      }
      iA += 2; iB += 2;
    }
    // drain A
    for (; iA + 2 <= cA; iA += 2) {
      int s0 = ssrc[stA + iA], s1 = ssrc[stA + iA + 1];
      short8 v0 = *(const short8*)(hc + (size_t)s0 * ic);
      short8 v1 = *(const short8*)(hc + (size_t)s1 * ic);
#pragma unroll
      for (int j = 0; j < 8; ++j)
        aA[j] += bits2f((unsigned short)v0[j]) + bits2f((unsigned short)v1[j]);
    }
    if (iA < cA) {
      int s0 = ssrc[stA + iA];
      short8 v0 = *(const short8*)(hc + (size_t)s0 * ic);
#pragma unroll
      for (int j = 0; j < 8; ++j) aA[j] += bits2f((unsigned short)v0[j]);
    }
    // drain B
    for (; iB + 2 <= cB; iB += 2) {
      int s0 = ssrc[stB + iB], s1 = ssrc[stB + iB + 1];
      short8 v0 = *(const short8*)(hc + (size_t)s0 * ic);
      short8 v1 = *(const short8*)(hc + (size_t)s1 * ic);
#pragma unroll
      for (int j = 0; j < 8; ++j)
        aB[j] += bits2f((unsigned short)v0[j]) + bits2f((unsigned short)v1[j]);
    }
    if (iB < cB) {
      int s0 = ssrc[stB + iB];
      short8 v0 = *(const short8*)(hc + (size_t)s0 * ic);
#pragma unroll
      for (int j = 0; j < 8; ++j) aB[j] += bits2f((unsigned short)v0[j]);
    }
    short8 oA, oB;
#pragma unroll
    for (int j = 0; j < 8; ++j) { oA[j] = f2bits(aA[j]); oB[j] = f2bits(aB[j]); }
    *(short8*)(agg + rowoff + rp * ic + cbase) = oA;
    *(short8*)(agg + rowoff + (rp + 4) * ic + cbase) = oB;
  }
}

// ---------------- split-N bf16 GEMM, bf16 out (conv layers): 128x64 tile, BK=128 ----------------
// Dual-source A: k0 < Kagg stages from AGG (stride Kagg); final ic-wide block
// stages from h directly (self/root operand never materialized). Deep K-step:
// 32 MFMA/wave per iteration, 2 barriers. As[128][128]+Ws[64][128] = 48 KB LDS.
// Staging: linear LDS dest + inverse-swizzled global source; reads via idx128.
__global__ __launch_bounds__(256) void gemm_f32_k(
    const bf16* __restrict__ A, const bf16* __restrict__ Hs,
    const bf16* __restrict__ Wt, bf16* __restrict__ Cb,
    int M, int N, int Kagg, int ic, int nb) {
  const int bid = blockIdx.x;
  const int xcd = bid & 7;
  const int slot = bid >> 3;
  const int gidx = slot / nb;
  const int member = slot - gidx * nb;
  const int mb = (M + 127) >> 7;
  const int m = gidx * 8 + xcd;
  if (m >= mb) return;
  const int m0 = m * 128;
  const int n0 = member * 64;
  const int K = Kagg + ic;    // weight K (9*ic)

  __shared__ __align__(16) bf16 As[128 * 128];
  __shared__ __align__(16) bf16 Ws[64 * 128];
  const int tid = threadIdx.x;
  const int wave = tid >> 6, lane = tid & 63;
  const int quad = lane >> 4, l16 = lane & 15;
  const int wm = (wave >> 1) * 64, wn = (wave & 1) * 32;
  floatx4 acc[4][2];
#pragma unroll
  for (int i = 0; i < 4; ++i)
#pragma unroll
    for (int j = 0; j < 2; ++j) acc[i][j] = (floatx4){0.f, 0.f, 0.f, 0.f};

  for (int k0 = 0; k0 < K; k0 += 128) {
    // As: 32 KB = 8 chunks/wave of 1 KB (4 rows x 16 slots each)
#pragma unroll
    for (int q = 0; q < 8; ++q) {
      int c0 = (wave * 8 + q) * 1024;
      int r = (c0 >> 8) + (lane >> 4);
      int grow = m0 + r; if (grow >= M) grow = M - 1;
      int s = lane & 15;
      int qg = ((s >> 3) << 3) | ((s & 7) ^ (r & 7));
      const bf16* src = (k0 < Kagg)
          ? (A + (size_t)grow * Kagg + k0 + qg * 8)
          : (Hs + (size_t)grow * ic + (k0 - Kagg) + qg * 8);
      async_copy16((char*)As + c0, src);
    }
    // Ws: 16 KB = 4 chunks/wave
#pragma unroll
    for (int q = 0; q < 4; ++q) {
      int c0 = (wave * 4 + q) * 1024;
      int r = (c0 >> 8) + (lane >> 4);
      int s = lane & 15;
      int qg = ((s >> 3) << 3) | ((s & 7) ^ (r & 7));
      async_copy16((char*)Ws + c0, Wt + (size_t)(n0 + r) * K + k0 + qg * 8);
    }
    __syncthreads();
#pragma unroll
    for (int kk = 0; kk < 4; ++kk) {
      int qg = kk * 4 + quad;
      short8 b0 = *(const short8*)(Ws + idx128(wn + l16, qg));
      short8 b1 = *(const short8*)(Ws + idx128(wn + 16 + l16, qg));
#pragma unroll
      for (int i = 0; i < 4; ++i) {
        short8 a = *(const short8*)(As + idx128(wm + i * 16 + l16, qg));
        acc[i][0] = __builtin_amdgcn_mfma_f32_16x16x32_bf16(a, b0, acc[i][0], 0, 0, 0);
        acc[i][1] = __builtin_amdgcn_mfma_f32_16x16x32_bf16(a, b1, acc[i][1], 0, 0, 0);
      }
    }
    __syncthreads();
  }
#pragma unroll
  for (int i = 0; i < 4; ++i)
#pragma unroll
    for (int j = 0; j < 2; ++j)
#pragma unroll
      for (int r = 0; r < 4; ++r) {
        int row = m0 + wm + i * 16 + quad * 4 + r;
        int col = n0 + wn + j * 16 + l16;
        if (row < M) Cb[(size_t)row * N + col] = f2b(acc[i][j][r]);
      }
}

// ---------------- plain bf16 GEMM (residuals, ZA): bf16 out, 64x64; grid (N/64, M/64) ----------------
__global__ __launch_bounds__(256) void gemm_plain_k(
    const bf16* __restrict__ A, const bf16* __restrict__ Wt,
    bf16* __restrict__ Cb, int M, int N, int K) {
  __shared__ __align__(16) bf16 As[64 * 64];
  __shared__ __align__(16) bf16 Ws[64 * 64];
  const int m0 = blockIdx.y * 64;
  const int n0 = blockIdx.x * 64;
  const int tid = threadIdx.x;
  const int wave = tid >> 6, lane = tid & 63;
  const int quad = lane >> 4, l16 = lane & 15;
  const int wm = (wave >> 1) * 32, wn = (wave & 1) * 32;
  floatx4 acc00 = {0.f, 0.f, 0.f, 0.f};
  floatx4 acc01 = acc00, acc10 = acc00, acc11 = acc00;

  for (int k0 = 0; k0 < K; k0 += 64) {
#pragma unroll
    for (int q = 0; q < 2; ++q) {
      int c0 = (wave * 2 + q) * 1024;
      int row = (c0 >> 7) + (lane >> 3);
      int grow = m0 + row; if (grow >= M) grow = M - 1;
      int ch = (lane & 7) ^ (row & 7);
      async_copy16((char*)As + c0, A + (size_t)grow * K + k0 + ch * 8);
    }
#pragma unroll
    for (int q = 0; q < 2; ++q) {
      int c0 = (wave * 2 + q) * 1024;
      int row = (c0 >> 7) + (lane >> 3);
      int ch = (lane & 7) ^ (row & 7);
      async_copy16((char*)Ws + c0, Wt + (size_t)(n0 + row) * K + k0 + ch * 8);
    }
    __syncthreads();
#pragma unroll
    for (int kk = 0; kk < 64; kk += 32) {
      int qb = (kk >> 3) + quad;
      short8 a0 = *frag_at(As, wm + l16, qb);
      short8 a1 = *frag_at(As, wm + 16 + l16, qb);
      short8 b0 = *frag_at(Ws, wn + l16, qb);
      short8 b1 = *frag_at(Ws, wn + 16 + l16, qb);
      acc00 = __builtin_amdgcn_mfma_f32_16x16x32_bf16(a0, b0, acc00, 0, 0, 0);
      acc01 = __builtin_amdgcn_mfma_f32_16x16x32_bf16(a0, b1, acc01, 0, 0, 0);
      acc10 = __builtin_amdgcn_mfma_f32_16x16x32_bf16(a1, b0, acc10, 0, 0, 0);
      acc11 = __builtin_amdgcn_mfma_f32_16x16x32_bf16(a1, b1, acc11, 0, 0, 0);
    }
    __syncthreads();
  }
  floatx4 accs[2][2] = {{acc00, acc01}, {acc10, acc11}};
#pragma unroll
  for (int i = 0; i < 2; ++i)
#pragma unroll
    for (int j = 0; j < 2; ++j)
#pragma unroll
      for (int r = 0; r < 4; ++r) {
        int row = m0 + wm + i * 16 + quad * 4 + r;
        int col = n0 + wn + j * 16 + l16;
        if (row < M) Cb[(size_t)row * N + col] = f2b(accs[i][j][r]);
      }
}

// ---------------- LN (+residual, +gelu) for conv layers ----------------
// conv bf16; short8 vector loads (16B/lane), lpr lanes per row.
__global__ __launch_bounds__(256) void ln_conv_k(
    const bf16* __restrict__ conv, const bf16* __restrict__ res,
    const float* __restrict__ g, const float* __restrict__ b,
    bf16* __restrict__ out, float* __restrict__ zout, int oc, int do_gelu) {
  const int lprsh = (oc == 256) ? 5 : 4;       // lanes per row = oc/8
  const int lpr = 1 << lprsh;
  const int rpb = 256 >> lprsh;
  int row = blockIdx.x * rpb + (threadIdx.x >> lprsh);
  if (row >= NN) return;
  int cb = (threadIdx.x & (lpr - 1)) * 8;
  short8 cv = *(const short8*)(conv + (size_t)row * oc + cb);
  float v[8];
  float s = 0.f, s2 = 0.f;
#pragma unroll
  for (int j = 0; j < 8; ++j) {
    v[j] = bits2f((unsigned short)cv[j]);
    s += v[j]; s2 += v[j] * v[j];
  }
  for (int off = lpr >> 1; off; off >>= 1) { s += __shfl_xor(s, off); s2 += __shfl_xor(s2, off); }
  float m = s / oc;
  float var = s2 / oc - m * m;
  float rs = rsqrtf(var + 1e-5f);
  short8 rv = *(const short8*)(res + (size_t)row * oc + cb);
  short8 ov;
#pragma unroll
  for (int j = 0; j < 8; ++j) {
    int c = cb + j;
    float y = (v[j] - m) * rs * g[c] + b[c];
    y += bits2f((unsigned short)rv[j]);
    if (zout) zout[(size_t)row * oc + c] = y;
    if (do_gelu) y = gelu_f(y);
    ov[j] = f2bits(y);
  }
  *(short8*)(out + (size_t)row * oc + cb) = ov;
}

// ---------------- decoder GEMM0 (nb=2, combined-K, XCD-pinned) ----------------
// P0[128 pairs][128 cols] per block; K=256 = prod128|diff128 via WPE.
__global__ __launch_bounds__(256) void gemm_pe_k(
    const bf16* __restrict__ z, const int* __restrict__ pairs,
    const bf16* __restrict__ WPE,  // [256 out][256 K]  (K = prod128 | diff128)
    bf16* __restrict__ P0) {
  const int bid = blockIdx.x;
  const int xcd = bid & 7;
  const int slot = bid >> 3;
  const int gidx = slot >> 1;          // nb = 2
  const int member = slot & 1;
  const int mb = (PP + 127) >> 7;
  const int m = gidx * 8 + xcd;
  if (m >= mb) return;
  const int m0 = m * 128;
  const int n0 = member * 128;

  __shared__ __align__(16) bf16 PEs[128 * 128];  // A tile: localk = prod64|diff64 of kwi
  __shared__ __align__(16) bf16 Ws[128 * 128];   // B tile: 128 cols x same localk
  const int tid = threadIdx.x;
  const int wave = tid >> 6, lane = tid & 63;
  const int quad = lane >> 4, l16 = lane & 15;
  const int wm = (wave >> 1) * 64, wn = (wave & 1) * 64;

  const int prow = tid >> 1;           // 0..127
  const int h = tid & 1;               // 32-col half of the 64-col z chunk
  int pp = m0 + prow; if (pp >= PP) pp = PP - 1;
  const bf16* zi = z + (size_t)pairs[pp] * 128;
  const bf16* zj = z + (size_t)pairs[PP + pp] * 128;

  floatx4 acc[4][4];
#pragma unroll
  for (int i = 0; i < 4; ++i)
#pragma unroll
    for (int j = 0; j < 4; ++j) acc[i][j] = (floatx4){0.f, 0.f, 0.f, 0.f};

#pragma unroll
  for (int kwi = 0; kwi < 2; ++kwi) {
    const int kw = kwi * 64;
    // z slice loads issued before the entry barrier (overlap the wait)
    short8 va[4], vb[4];
#pragma unroll
    for (int c8 = 0; c8 < 4; ++c8) {
      va[c8] = *(const short8*)(zi + kw + h * 32 + c8 * 8);
      vb[c8] = *(const short8*)(zj + kw + h * 32 + c8 * 8);
    }
    if (kwi) __syncthreads();          // waves done reading PEs/Ws of prev phase
    // stage Ws[128][128] via async: pre-swizzled global source, linear LDS dest.
#pragma unroll
    for (int q = 0; q < 8; ++q) {
      int c0 = (wave * 8 + q) * 1024;              // byte offset (1KB = 4 rows)
      int r = (c0 >> 8) + (lane >> 4);
      int s = lane & 15;
      async_copy16((char*)Ws + c0,
                   WPE + (size_t)(n0 + r) * 256 + ((s >> 3) << 7) + kw + (((s & 7) ^ (r & 7)) << 3));
    }
    // build PEs: localk 0..63 = prod, 64..127 = absdiff (both ops, one pass)
#pragma unroll
    for (int c8 = 0; c8 < 4; ++c8) {
      short8 op, od;
#pragma unroll
      for (int jj = 0; jj < 8; ++jj) {
        float fa = bits2f((unsigned short)va[c8][jj]);
        float fb = bits2f((unsigned short)vb[c8][jj]);
        op[jj] = f2bits(fa * fb);
        od[jj] = f2bits(fabsf(fa - fb));
      }
      *(short8*)(PEs + idx128(prow, h * 4 + c8)) = op;
      *(short8*)(PEs + idx128(prow, 8 + h * 4 + c8)) = od;
    }
    __syncthreads();                   // drains async vmcnt + PE writes
    // MFMA over localk=128 (4 slices of 32)
#pragma unroll
    for (int ks = 0; ks < 4; ++ks) {
      const int qg = ks * 4 + quad;
      short8 bfr[4];
#pragma unroll
      for (int j = 0; j < 4; ++j)
        bfr[j] = *(const short8*)(Ws + idx128(wn + j * 16 + l16, qg));
#pragma unroll
      for (int i = 0; i < 4; ++i) {
        short8 a = *(const short8*)(PEs + idx128(wm + i * 16 + l16, qg));
#pragma unroll
        for (int j = 0; j < 4; ++j)
          acc[i][j] = __builtin_amdgcn_mfma_f32_16x16x32_bf16(a, bfr[j], acc[i][j], 0, 0, 0);
      }
    }
  }

#pragma unroll
  for (int i = 0; i < 4; ++i)
#pragma unroll
    for (int j = 0; j < 4; ++j)
#pragma unroll
      for (int r = 0; r < 4; ++r) {
        int row = m0 + wm + i * 16 + quad * 4 + r;
        int col = n0 + wn + j * 16 + l16;
        if (row < PP) P0[(size_t)row * 256 + col] = f2b(acc[i][j][r]);
      }
}

// ---------------- elementwise: D0 = gelu(ln(P0 + ZA[gi] + ZA[gj] + db0)) in place ----------------
__global__ __launch_bounds__(256) void ln_d0_k(bf16* __restrict__ D0,
                                               const int* __restrict__ pairs,
                                               const bf16* __restrict__ ZA,
                                               const float* __restrict__ db0,
                                               const float* __restrict__ g,
                                               const float* __restrict__ b) {
  const int wave = threadIdx.x >> 6, lane = threadIdx.x & 63;
  const int row = blockIdx.x * 8 + wave * 2 + (lane >> 5);   // PP % 8 == 0
  const int cb = (lane & 31) * 8;
  int gi = pairs[row], gj = pairs[PP + row];
  bf16* p = D0 + (size_t)row * 256 + cb;
  short8 xv = *(const short8*)p;
  short8 av = *(const short8*)(ZA + (size_t)gi * 256 + cb);
  short8 bv = *(const short8*)(ZA + (size_t)gj * 256 + cb);
  float v[8];
  float s = 0.f, s2 = 0.f;
#pragma unroll
  for (int k = 0; k < 8; ++k) {
    v[k] = bits2f((unsigned short)xv[k]) + bits2f((unsigned short)av[k]) +
           bits2f((unsigned short)bv[k]) + db0[cb + k];
    s += v[k]; s2 += v[k] * v[k];
  }
  // reduce within each 32-lane half (one row per half)
  for (int off = 16; off; off >>= 1) { s += __shfl_xor(s, off); s2 += __shfl_xor(s2, off); }
  float m = s / 256.f;
  float var = s2 / 256.f - m * m;
  float rs = rsqrtf(var + 1e-5f);
  short8 ov;
#pragma unroll
  for (int k = 0; k < 8; ++k) {
    float y = (v[k] - m) * rs * g[cb + k] + b[cb + k];
    ov[k] = f2bits(gelu_f(y));
  }
  *(short8*)p = ov;
}

// ---------------- decoder GEMM1: A = D0 (bf16) staged; P1 = A@W1^T + db1 ----------------
__global__ __launch_bounds__(256) void lngemm1_k(
    const bf16* __restrict__ D0, const bf16* __restrict__ W1t,  // [128][256]
    const float* __restrict__ bias, bf16* __restrict__ P1, int M) {
  __shared__ __align__(16) bf16 As[64 * 256];
  __shared__ __align__(16) bf16 Ws[128 * 64];
  const int tid = threadIdx.x;
  const int wave = tid >> 6, lane = tid & 63;
  const int quad = lane >> 4, l16 = lane & 15;
  const int wr = (wave >> 1) * 32;
  const int wc = (wave & 1) * 64;
  const int m0 = blockIdx.x * 64;

  // stage A (already post-LN/GELU bf16)
  {
    const int srow = tid >> 2;
    const int q4 = tid & 3;
    int grow = m0 + srow; if (grow >= M) grow = M - 1;
    const bf16* src = D0 + (size_t)grow * 256 + q4 * 64;
#pragma unroll
    for (int c8 = 0; c8 < 8; ++c8) {
      short8 o = *(const short8*)(src + c8 * 8);
      *(short8*)(As + srow * 256 + q4 * 64 + ((c8 ^ (srow & 7)) << 3)) = o;
    }
  }

  floatx4 acc[2][4];
#pragma unroll
  for (int i = 0; i < 2; ++i)
#pragma unroll
    for (int j = 0; j < 4; ++j) acc[i][j] = (floatx4){0.f, 0.f, 0.f, 0.f};

  for (int kc = 0; kc < 4; ++kc) {
#pragma unroll
    for (int q = 0; q < 4; ++q) {
      int c0 = q * 4096 + wave * 1024;
      int row = (c0 >> 7) + (lane >> 3);
      int ch = (lane & 7) ^ (row & 7);
      async_copy16((char*)Ws + c0, W1t + (size_t)row * 256 + kc * 64 + ch * 8);
    }
    __syncthreads();
#pragma unroll
    for (int kk = 0; kk < 64; kk += 32) {
      int qb = (kk >> 3) + quad;
      short8 a0 = *frag256(As, wr + l16, kc * 64, qb);
      short8 a1 = *frag256(As, wr + 16 + l16, kc * 64, qb);
#pragma unroll
      for (int j = 0; j < 4; ++j) {
        short8 bb = *frag_at(Ws, wc + j * 16 + l16, qb);
        acc[0][j] = __builtin_amdgcn_mfma_f32_16x16x32_bf16(a0, bb, acc[0][j], 0, 0, 0);
        acc[1][j] = __builtin_amdgcn_mfma_f32_16x16x32_bf16(a1, bb, acc[1][j], 0, 0, 0);
      }
    }
    __syncthreads();
  }

#pragma unroll
  for (int i = 0; i < 2; ++i)
#pragma unroll
    for (int r = 0; r < 4; ++r) {
      int row = wr + i * 16 + quad * 4 + r;
      int grow = m0 + row;
      if (grow >= M) continue;
#pragma unroll
      for (int j = 0; j < 4; ++j) {
        int col = wc + j * 16 + l16;
        P1[(size_t)grow * 128 + col] = f2b(acc[i][j][r] + bias[col]);
      }
    }
}

// ---------------- decoder GEMM2 + logits (fused): A = gelu(ln(P1));
// t = gelu(ln(A@W2^T + db2)) . w3 + b3  -> out[p].  LN(64) + dot done
// in-register via shfl within each 16-lane quad group. ----------------
__global__ __launch_bounds__(256) void lngemm2_k(
    const bf16* __restrict__ P1, const bf16* __restrict__ W2t,  // [64][128]
    const float* __restrict__ g, const float* __restrict__ b,
    const float* __restrict__ bias,
    const float* __restrict__ g2, const float* __restrict__ b2,
    const float* __restrict__ w3, const float* __restrict__ b3,
    float* __restrict__ out, int M) {
  __shared__ __align__(16) bf16 As[64 * 128];
  __shared__ __align__(16) bf16 Ws[64 * 64];
  const int tid = threadIdx.x;
  const int wave = tid >> 6, lane = tid & 63;
  const int quad = lane >> 4, l16 = lane & 15;
  const int m0 = blockIdx.x * 64;

  {
    const int srow = tid >> 2;
    const int q4 = tid & 3;
    int grow = m0 + srow; if (grow >= M) grow = M - 1;
    const bf16* src = P1 + (size_t)grow * 128 + q4 * 32;
    float v[32];
    float s = 0.f, s2 = 0.f;
#pragma unroll
    for (int c8 = 0; c8 < 4; ++c8) {
      short8 x = *(const short8*)(src + c8 * 8);
#pragma unroll
      for (int jj = 0; jj < 8; ++jj) {
        float f = bits2f((unsigned short)x[jj]);
        v[c8 * 8 + jj] = f; s += f; s2 += f * f;
      }
    }
    s += __shfl_xor(s, 1); s2 += __shfl_xor(s2, 1);
    s += __shfl_xor(s, 2); s2 += __shfl_xor(s2, 2);
    float mean = s / 128.f;
    float var = s2 / 128.f - mean * mean;
    float rs = rsqrtf(var + 1e-5f);
#pragma unroll
    for (int c8 = 0; c8 < 4; ++c8) {
      short8 o;
#pragma unroll
      for (int jj = 0; jj < 8; ++jj) {
        int col = q4 * 32 + c8 * 8 + jj;
        float y = (v[c8 * 8 + jj] - mean) * rs * g[col] + b[col];
        o[jj] = f2bits(gelu_f(y));
      }
      *(short8*)(As + idx128(srow, q4 * 4 + c8)) = o;
    }
  }

  floatx4 acc[4];
#pragma unroll
  for (int j = 0; j < 4; ++j) acc[j] = (floatx4){0.f, 0.f, 0.f, 0.f};

  for (int kc = 0; kc < 2; ++kc) {
#pragma unroll
    for (int q = 0; q < 2; ++q) {
      int c0 = q * 4096 + wave * 1024;
      int row = (c0 >> 7) + (lane >> 3);
      int ch = (lane & 7) ^ (row & 7);
      async_copy16((char*)Ws + c0, W2t + (size_t)row * 128 + kc * 64 + ch * 8);
    }
    __syncthreads();
#pragma unroll
    for (int kk = 0; kk < 64; kk += 32) {
      int qb = (kk >> 3) + quad;
      short8 a = *(const short8*)(As + idx128(wave * 16 + l16, kc * 8 + qb));
#pragma unroll
      for (int j = 0; j < 4; ++j) {
        short8 bb = *frag_at(Ws, j * 16 + l16, qb);
        acc[j] = __builtin_amdgcn_mfma_f32_16x16x32_bf16(a, bb, acc[j], 0, 0, 0);
      }
    }
    __syncthreads();
  }

  // fused epilogue: per row (owned by 16 contiguous lanes of this quad group):
  // y = acc + db2; LN over 64; gelu; dot with w3; write out[row].
#pragma unroll
  for (int r = 0; r < 4; ++r) {
    int row = wave * 16 + quad * 4 + r;
    int grow = m0 + row;
    float y[4];
    float s = 0.f, s2 = 0.f;
#pragma unroll
    for (int j = 0; j < 4; ++j) {
      int col = j * 16 + l16;
      y[j] = acc[j][r] + bias[col];
      s += y[j]; s2 += y[j] * y[j];
    }
    for (int off = 8; off; off >>= 1) { s += __shfl_xor(s, off); s2 += __shfl_xor(s2, off); }
    float mean = s / 64.f;
    float var = s2 / 64.f - mean * mean;
    float rs = rsqrtf(var + 1e-5f);
    float t = 0.f;
#pragma unroll
    for (int j = 0; j < 4; ++j) {
      int col = j * 16 + l16;
      float yy = gelu_f((y[j] - mean) * rs * g2[col] + b2[col]);
      t += yy * w3[col];
    }
    for (int off = 8; off; off >>= 1) t += __shfl_xor(t, off);
    if (l16 == 0 && grow < M) out[grow] = t + b3[0];
  }
}

// ---------------- host ----------------
extern "C" void kernel_launch(void* const* d_in, const int* in_sizes, int n_in,
                              void* d_out, int out_size, void* d_ws, size_t ws_size,
                              hipStream_t stream) {
  auto cdiv = [](int a, int b) { return (a + b - 1) / b; };

  const float* x = (const float*)d_in[0];
  const int* ei = (const int*)d_in[1];
  const int* et = (const int*)d_in[2];
  const int* gp = (const int*)d_in[3];
  const float *basis[4], *att[4], *root[4], *relatt[4], *gln[4], *bln[4];
  for (int l = 0; l < 4; ++l) {
    basis[l]  = (const float*)d_in[4 + 6 * l];
    att[l]    = (const float*)d_in[5 + 6 * l];
    root[l]   = (const float*)d_in[6 + 6 * l];
    relatt[l] = (const float*)d_in[7 + 6 * l];
    gln[l]    = (const float*)d_in[8 + 6 * l];
    bln[l]    = (const float*)d_in[9 + 6 * l];
  }
  const float* res0 = (const float*)d_in[28];
  const float* res3 = (const float*)d_in[29];
  const float* dW0 = (const float*)d_in[30]; const float* db0 = (const float*)d_in[31];
  const float* dg0 = (const float*)d_in[32]; const float* dbb0 = (const float*)d_in[33];
  const float* dW1 = (const float*)d_in[34]; const float* db1 = (const float*)d_in[35];
  const float* dg1 = (const float*)d_in[36]; const float* dbb1 = (const float*)d_in[37];
  const float* dW2 = (const float*)d_in[38]; const float* db2 = (const float*)d_in[39];
  const float* dg2 = (const float*)d_in[40]; const float* dbb2 = (const float*)d_in[41];
  const float* dW3 = (const float*)d_in[42]; const float* db3 = (const float*)d_in[43];

  char* base = (char*)d_ws;
  size_t off = 0;
  auto alloc = [&](size_t bytes) -> char* {
    char* p = base + off;
    off += (bytes + 255) & ~(size_t)255;
    return p;
  };
  bf16* X16 = (bf16*)alloc((size_t)NN * 128 * 2);
  bf16* HA  = (bf16*)alloc((size_t)NN * 256 * 2);
  bf16* HB  = (bf16*)alloc((size_t)NN * 256 * 2);
  bf16* RESB = (bf16*)alloc((size_t)NN * 256 * 2);
  bf16* ZA   = (bf16*)alloc((size_t)NN * 256 * 2);
  bf16* CONV = (bf16*)alloc((size_t)NN * 256 * 2);
  bf16* WT    = (bf16*)alloc((size_t)589824 * 2);
  bf16* RES0T = (bf16*)alloc((size_t)32768 * 2);
  bf16* RES3T = (bf16*)alloc((size_t)32768 * 2);
  bf16* WAT   = (bf16*)alloc((size_t)32768 * 2);
  bf16* WPE   = (bf16*)alloc((size_t)65536 * 2);   // [256][256] combined prod|diff W^T
  bf16* DW1T  = (bf16*)alloc((size_t)32768 * 2);
  bf16* DW2T  = (bf16*)alloc((size_t)8192 * 2);
  float* ASOFT = (float*)alloc(32 * 4);
  int* COUNTS = (int*)alloc((size_t)NR * 4);
  int* SEG    = (int*)alloc((size_t)NR * 4);
  int* CUR    = (int*)alloc((size_t)NR * 4);
  int* BS     = (int*)alloc(1024 * 4);
  int* SSRC   = (int*)alloc((size_t)EE * 4);
  char* BIG = alloc(93000000);   // overlay: AGG [N,2048]bf16 (82MB) | P0/D0 [P,256]bf16 (51.2MB)
  bf16* AGG = (bf16*)BIG;
  bf16* P0  = (bf16*)BIG;
  bf16* P1  = (bf16*)alloc((size_t)PP * 128 * 2);
  (void)ws_size; (void)in_sizes; (void)n_in; (void)out_size;

  float* out_logits = (float*)d_out;
  float* out_z = (float*)d_out + PP;

  // --- CSR build ---
  hipMemsetAsync(COUNTS, 0, (size_t)NR * 4, stream);
  hipMemsetAsync(CUR, 0, (size_t)NR * 4, stream);
  hist_k<<<cdiv(EE, 256), 256, 0, stream>>>(ei + EE, et, COUNTS);
  scan1_k<<<NR / 256, 256, 0, stream>>>(COUNTS, SEG, BS);
  scan2_k<<<1, 256, 0, stream>>>(BS, NR / 256);
  scan3_k<<<NR / 256, 256, 0, stream>>>(SEG, BS);
  scatter_k<<<cdiv(EE, 256), 256, 0, stream>>>(ei, ei + EE, et, SEG, CUR, SSRC);

  // --- weight prep ---
  cvt_bf16_k<<<cdiv(NN * 128, 256), 256, 0, stream>>>(x, X16, NN * 128);
  softmax4_k<<<1, 64, 0, stream>>>(relatt[0], relatt[1], relatt[2], relatt[3], ASOFT);
  prep_small_k<<<cdiv(172032, 256), 256, 0, stream>>>(res0, res3, dW0, dW1, dW2,
                                                      RES0T, RES3T, WAT, WPE, DW1T, DW2T);

  const int mb = cdiv(NN, 128);            // 157
  const int swzP4 = 8 * cdiv(mb, 8) * 4;   // nb=4
  const int swzP2 = 8 * cdiv(mb, 8) * 2;   // nb=2

  // --- layer 0: ic=128, oc=256, residual = x @ res0 ---
  prep_w_k<<<cdiv(9 * 128 * 256, 256), 256, 0, stream>>>(basis[0], att[0], root[0], ASOFT + 0, WT, 128, 7, 256, 8);
  aggregate_k<<<cdiv(NN, 16), 256, 0, stream>>>(X16, SEG, COUNTS, SSRC, AGG, 128, 4);
  gemm_plain_k<<<dim3(4, cdiv(NN, 64)), 256, 0, stream>>>(X16, RES0T, RESB, NN, 256, 128);
  gemm_f32_k<<<swzP4, 256, 0, stream>>>(AGG, X16, WT, CONV, NN, 256, 1024, 128, 4);
  ln_conv_k<<<cdiv(NN, 8), 256, 0, stream>>>(CONV, RESB, gln[0], bln[0], HA, nullptr, 256, 1);

  // --- layer 1 ---
  prep_w_k<<<cdiv(9 * 256 * 256, 256), 256, 0, stream>>>(basis[1], att[1], root[1], ASOFT + 8, WT, 256, 8, 256, 8);
  aggregate_k<<<cdiv(NN, 8), 256, 0, stream>>>(HA, SEG, COUNTS, SSRC, AGG, 256, 5);
  gemm_f32_k<<<swzP4, 256, 0, stream>>>(AGG, HA, WT, CONV, NN, 256, 2048, 256, 4);
  ln_conv_k<<<cdiv(NN, 8), 256, 0, stream>>>(CONV, HA, gln[1], bln[1], HB, nullptr, 256, 1);

  // --- layer 2 ---
  prep_w_k<<<cdiv(9 * 256 * 256, 256), 256, 0, stream>>>(basis[2], att[2], root[2], ASOFT + 16, WT, 256, 8, 256, 8);
  aggregate_k<<<cdiv(NN, 8), 256, 0, stream>>>(HB, SEG, COUNTS, SSRC, AGG, 256, 5);
  gemm_f32_k<<<swzP4, 256, 0, stream>>>(AGG, HB, WT, CONV, NN, 256, 2048, 256, 4);
  ln_conv_k<<<cdiv(NN, 8), 256, 0, stream>>>(CONV, HB, gln[2], bln[2], HA, nullptr, 256, 1);

  // --- layer 3: oc=128, residual = h_in @ res3, no gelu; writes z (fp32 out_z) + HB ---
  prep_w_k<<<cdiv(9 * 256 * 128, 256), 256, 0, stream>>>(basis[3], att[3], root[3], ASOFT + 24, WT, 256, 8, 128, 7);
  aggregate_k<<<cdiv(NN, 8), 256, 0, stream>>>(HA, SEG, COUNTS, SSRC, AGG, 256, 5);
  gemm_plain_k<<<dim3(2, cdiv(NN, 64)), 256, 0, stream>>>(HA, RES3T, RESB, NN, 128, 256);
  gemm_f32_k<<<swzP2, 256, 0, stream>>>(AGG, HA, WT, CONV, NN, 128, 2048, 256, 2);
  ln_conv_k<<<cdiv(NN, 16), 256, 0, stream>>>(CONV, RESB, gln[3], bln[3], HB, out_z, 128, 0);

  // --- decoder ---
  gemm_plain_k<<<dim3(4, cdiv(NN, 64)), 256, 0, stream>>>(HB, WAT, ZA, NN, 256, 128);
  const int pb = cdiv(PP, 128);            // 782
  const int swzPE = 8 * cdiv(pb, 8) * 2;   // nb=2
  gemm_pe_k<<<swzPE, 256, 0, stream>>>(HB, gp, WPE, P0);
  ln_d0_k<<<cdiv(PP, 8), 256, 0, stream>>>(P0, gp, ZA, db0, dg0, dbb0);
  lngemm1_k<<<cdiv(PP, 64), 256, 0, stream>>>(P0, DW1T, db1, P1, PP);
  lngemm2_k<<<cdiv(PP, 64), 256, 0, stream>>>(P1, DW2T, dg1, dbb1, db2, dg2, dbb2,
                                              dW3, db3, out_logits, PP);
}

// Round 11
// 684.453 us; speedup vs baseline: 1.0169x; 1.0084x over previous
//
#include <hip/hip_runtime.h>
#include <hip/hip_bf16.h>
#include <math.h>
#include <cstddef>
#include <stdint.h>

#define NN 20000
#define EE 320000
#define RR 8
#define PP 100000
#define NR (NN * RR)   // 160000 = 625*256

typedef __hip_bfloat16 bf16;
typedef __attribute__((ext_vector_type(8))) short short8;
typedef __attribute__((ext_vector_type(4))) short short4v;
typedef __attribute__((ext_vector_type(4))) float floatx4;
typedef __attribute__((ext_vector_type(4))) int intx4;

__device__ __forceinline__ float b2f(bf16 v) { return __bfloat162float(v); }
__device__ __forceinline__ bf16 f2b(float v) { return __float2bfloat16(v); }
__device__ __forceinline__ float bits2f(unsigned short u) {
  unsigned int i = ((unsigned int)u) << 16; float f; __builtin_memcpy(&f, &i, 4); return f;
}
__device__ __forceinline__ short f2bits(float f) {
  bf16 h = __float2bfloat16(f); short s; __builtin_memcpy(&s, &h, 2); return s;
}
// fast tanh-form gelu: x*sigmoid(2t), t = 0.79788456*(x + 0.044715*x^3).
// 0.5*(1+tanh(t)) == 1/(1+e^{-2t}) == rcp(1 + 2^{-2.885390082*t}).
// max |delta| vs exact-erf gelu ~3e-4 << bf16 quantization noise.
__device__ __forceinline__ float gelu_f(float x) {
  float t = x * (0.7978845608f + 0.0356774081f * x * x);
  float s = exp2f(-2.885390082f * t);
  return x * __builtin_amdgcn_rcpf(1.f + s);
}
// async global->LDS, 16B per lane; lds base wave-uniform, lane i lands at base+i*16
__device__ __forceinline__ void async_copy16(void* lds, const void* g) {
  __builtin_amdgcn_global_load_lds((const __attribute__((address_space(1))) void*)g,
                                   (__attribute__((address_space(3))) void*)lds, 16, 0, 0);
}
// swizzled fragment address, [rows][64] bf16 tile (stride 64): chunk q lives at q^(row&7)
__device__ __forceinline__ const short8* frag_at(const bf16* base, int row, int q) {
  return (const short8*)(base + row * 64 + (((q) ^ (row & 7)) << 3));
}
// stride-256 variant (col64 = 64-col group base), and stride-128 variant (qg = global chunk)
__device__ __forceinline__ const short8* frag256(const bf16* base, int row, int col64, int q) {
  return (const short8*)(base + row * 256 + col64 + (((q) ^ (row & 7)) << 3));
}
__device__ __forceinline__ int idx128(int row, int qg) {
  return row * 128 + ((qg >> 3) << 6) + (((qg & 7) ^ (row & 7)) << 3);
}

// ---------------- CSR build ----------------
__global__ void hist_k(const int* __restrict__ dst, const int* __restrict__ et,
                       int* __restrict__ counts) {
  int e = blockIdx.x * 256 + threadIdx.x;
  if (e >= EE) return;
  atomicAdd(&counts[dst[e] * RR + et[e]], 1);
}

__global__ void scan1_k(const int* __restrict__ counts, int* __restrict__ prefix,
                        int* __restrict__ bsums) {
  __shared__ int tmp[256];
  int i = blockIdx.x * 256 + threadIdx.x;
  int v = counts[i];
  tmp[threadIdx.x] = v; __syncthreads();
  for (int off = 1; off < 256; off <<= 1) {
    int x = (threadIdx.x >= off) ? tmp[threadIdx.x - off] : 0;
    __syncthreads();
    tmp[threadIdx.x] += x;
    __syncthreads();
  }
  prefix[i] = tmp[threadIdx.x] - v;
  if (threadIdx.x == 255) bsums[blockIdx.x] = tmp[255];
}

__global__ void scan2_k(int* __restrict__ bsums, int nb) {
  __shared__ int tmp[256];
  __shared__ int carry;
  if (threadIdx.x == 0) carry = 0;
  __syncthreads();
  for (int base = 0; base < nb; base += 256) {
    int i = base + threadIdx.x;
    int v = (i < nb) ? bsums[i] : 0;
    tmp[threadIdx.x] = v; __syncthreads();
    for (int off = 1; off < 256; off <<= 1) {
      int x = (threadIdx.x >= off) ? tmp[threadIdx.x - off] : 0;
      __syncthreads();
      tmp[threadIdx.x] += x;
      __syncthreads();
    }
    int c = carry;
    if (i < nb) bsums[i] = c + tmp[threadIdx.x] - v;
    __syncthreads();
    if (threadIdx.x == 255) carry = c + tmp[255];
    __syncthreads();
  }
}

__global__ void scan3_k(int* __restrict__ prefix, const int* __restrict__ bsums) {
  int i = blockIdx.x * 256 + threadIdx.x;
  prefix[i] += bsums[blockIdx.x];
}

__global__ void scatter_k(const int* __restrict__ src, const int* __restrict__ dst,
                          const int* __restrict__ et, const int* __restrict__ segstart,
                          int* __restrict__ cursor, int* __restrict__ ssrc) {
  int e = blockIdx.x * 256 + threadIdx.x;
  if (e >= EE) return;
  int s = dst[e] * RR + et[e];
  int pos = atomicAdd(&cursor[s], 1);
  ssrc[segstart[s] + pos] = src[e];
}

// ---------------- small prep kernels ----------------
__global__ void cvt_bf16_k(const float* __restrict__ in, bf16* __restrict__ out, int n) {
  int i = blockIdx.x * 256 + threadIdx.x;
  if (i < n) out[i] = f2b(in[i]);
}

// all small weight transposes batched into ONE launch
__global__ void prep_small_k(const float* __restrict__ res0, const float* __restrict__ res3,
                             const float* __restrict__ dW0, const float* __restrict__ dW1,
                             const float* __restrict__ dW2,
                             bf16* __restrict__ RES0T, bf16* __restrict__ RES3T,
                             bf16* __restrict__ WAT, bf16* __restrict__ WPE,
                             bf16* __restrict__ DW1T, bf16* __restrict__ DW2T) {
  int idx = blockIdx.x * 256 + threadIdx.x;
  if (idx < 32768) {                         // res0 [128][256] -> T
    int r = idx >> 8, c = idx & 255;
    RES0T[(size_t)c * 128 + r] = f2b(res0[idx]);
  } else if (idx < 65536) {                  // res3 [256][128] -> T
    int i2 = idx - 32768; int r = i2 >> 7, c = i2 & 127;
    RES3T[(size_t)c * 256 + r] = f2b(res3[i2]);
  } else if (idx < 98304) {                  // WA = dW0[0:128] [128][256] -> T
    int i2 = idx - 65536; int r = i2 >> 8, c = i2 & 255;
    WAT[(size_t)c * 128 + r] = f2b(dW0[i2]);
  } else if (idx < 131072) {                 // WPE: prod|diff combined K
    int i2 = idx - 98304; int k = i2 >> 8, o = i2 & 255;
    WPE[(size_t)o * 256 + k] = f2b(dW0[128 * 256 + i2]);
    WPE[(size_t)o * 256 + 128 + k] = f2b(dW0[256 * 256 + i2]);
  } else if (idx < 163840) {                 // dW1 [256][128] -> T
    int i2 = idx - 131072; int r = i2 >> 7, c = i2 & 127;
    DW1T[(size_t)c * 256 + r] = f2b(dW1[i2]);
  } else if (idx < 172032) {                 // dW2 [128][64] -> T
    int i2 = idx - 163840; int r = i2 >> 6, c = i2 & 63;
    DW2T[(size_t)c * 128 + r] = f2b(dW2[i2]);
  }
}

// ---------------- conv-weight prep, ALL 4 layers in one launch ----------------
// Each thread owns (k,o) of one layer: reads the 8 basis values ONCE (was 8x),
// computes relation-softmax inline (8 exps, L1-hot relatt), writes all 9
// Wt[o][r*ic+k] outputs. Replaces 4 prep_w launches + softmax4_k.
__global__ void prep_w_all_k(
    const float* __restrict__ basis0, const float* __restrict__ att0,
    const float* __restrict__ root0,  const float* __restrict__ ra0,
    const float* __restrict__ basis1, const float* __restrict__ att1,
    const float* __restrict__ root1,  const float* __restrict__ ra1,
    const float* __restrict__ basis2, const float* __restrict__ att2,
    const float* __restrict__ root2,  const float* __restrict__ ra2,
    const float* __restrict__ basis3, const float* __restrict__ att3,
    const float* __restrict__ root3,  const float* __restrict__ ra3,
    bf16* __restrict__ W0, bf16* __restrict__ W1,
    bf16* __restrict__ W2, bf16* __restrict__ W3) {
  int idx = blockIdx.x * 256 + threadIdx.x;
  const float *basis, *att, *root, *ra;
  bf16* Wt;
  int ic, ocsh, i2;
  if (idx < 32768)       { basis = basis0; att = att0; root = root0; ra = ra0; Wt = W0; ic = 128; ocsh = 8; i2 = idx; }
  else if (idx < 98304)  { basis = basis1; att = att1; root = root1; ra = ra1; Wt = W1; ic = 256; ocsh = 8; i2 = idx - 32768; }
  else if (idx < 163840) { basis = basis2; att = att2; root = root2; ra = ra2; Wt = W2; ic = 256; ocsh = 8; i2 = idx - 98304; }
  else if (idx < 196608) { basis = basis3; att = att3; root = root3; ra = ra3; Wt = W3; ic = 256; ocsh = 7; i2 = idx - 163840; }
  else return;
  const int oc = 1 << ocsh;
  const int o = i2 & (oc - 1);
  const int k = i2 >> ocsh;
  const int cols = 9 * ic;
  // relation softmax (tiny, recomputed per thread)
  float mx = -1e30f;
#pragma unroll
  for (int i = 0; i < RR; ++i) mx = fmaxf(mx, ra[i]);
  float e[RR]; float ssum = 0.f;
#pragma unroll
  for (int i = 0; i < RR; ++i) { e[i] = expf(ra[i] - mx); ssum += e[i]; }
  float rsum = 1.f / ssum;
  // basis column (read once)
  float bv[RR];
#pragma unroll
  for (int bb = 0; bb < RR; ++bb) bv[bb] = basis[((size_t)bb * ic + k) * oc + o];
#pragma unroll
  for (int r = 0; r < RR; ++r) {
    float acc = 0.f;
#pragma unroll
    for (int bb = 0; bb < RR; ++bb) acc += att[r * RR + bb] * bv[bb];
    Wt[(size_t)o * cols + r * ic + k] = f2b(e[r] * rsum * acc);
  }
  Wt[(size_t)o * cols + 8 * ic + k] = f2b(root[(size_t)k * oc + o]);
}

// ---------------- aggregation (segment sums; self row NOT materialized) ----------------
// AGG stride = 8*ic (self/root A-operand is read straight from h in the GEMM).
__global__ __launch_bounds__(256) void aggregate_k(
    const bf16* __restrict__ h, const int* __restrict__ segstart,
    const int* __restrict__ counts, const int* __restrict__ ssrc,
    bf16* __restrict__ agg, int ic, int tpnsh) {
  int tpn = 1 << tpnsh;
  int npb = 256 >> tpnsh;
  int local = threadIdx.x >> tpnsh;
  int n = blockIdx.x * npb + local;
  if (n >= NN) return;
  int cbase = (threadIdx.x & (tpn - 1)) * 8;
  size_t rowoff = (size_t)n * (8 * ic);
  const bf16* hc = h + cbase;

  // hoist all metadata: 4 vector loads, issued up front
  intx4 stv0 = *(const intx4*)(segstart + n * RR);
  intx4 stv1 = *(const intx4*)(segstart + n * RR + 4);
  intx4 ctv0 = *(const intx4*)(counts + n * RR);
  intx4 ctv1 = *(const intx4*)(counts + n * RR + 4);
  int sts[8] = {stv0[0], stv0[1], stv0[2], stv0[3], stv1[0], stv1[1], stv1[2], stv1[3]};
  int cts[8] = {ctv0[0], ctv0[1], ctv0[2], ctv0[3], ctv1[0], ctv1[1], ctv1[2], ctv1[3]};

#pragma unroll
  for (int rp = 0; rp < 4; ++rp) {
    const int stA = sts[rp],     cA = cts[rp];
    const int stB = sts[rp + 4], cB = cts[rp + 4];
    float aA[8] = {0.f, 0.f, 0.f, 0.f, 0.f, 0.f, 0.f, 0.f};
    float aB[8] = {0.f, 0.f, 0.f, 0.f, 0.f, 0.f, 0.f, 0.f};
    int iA = 0, iB = 0;
    // steady state: 4 gathers in flight
    while (iA + 2 <= cA && iB + 2 <= cB) {
      int sA0 = ssrc[stA + iA], sA1 = ssrc[stA + iA + 1];
      int sB0 = ssrc[stB + iB], sB1 = ssrc[stB + iB + 1];
      short8 vA0 = *(const short8*)(hc + (size_t)sA0 * ic);
      short8 vA1 = *(const short8*)(hc + (size_t)sA1 * ic);
      short8 vB0 = *(const short8*)(hc + (size_t)sB0 * ic);
      short8 vB1 = *(const short8*)(hc + (size_t)sB1 * ic);
#pragma unroll
      for (int j = 0; j < 8; ++j) {
        aA[j] += bits2f((unsigned short)vA0[j]) + bits2f((unsigned short)vA1[j]);
        aB[j] += bits2f((unsigned short)vB0[j]) + bits2f((unsigned short)vB1[j]);
      }
      iA += 2; iB += 2;
    }
    // drain A
    for (; iA + 2 <= cA; iA += 2) {
      int s0 = ssrc[stA + iA], s1 = ssrc[stA + iA + 1];
      short8 v0 = *(const short8*)(hc + (size_t)s0 * ic);
      short8 v1 = *(const short8*)(hc + (size_t)s1 * ic);
#pragma unroll
      for (int j = 0; j < 8; ++j)
        aA[j] += bits2f((unsigned short)v0[j]) + bits2f((unsigned short)v1[j]);
    }
    if (iA < cA) {
      int s0 = ssrc[stA + iA];
      short8 v0 = *(const short8*)(hc + (size_t)s0 * ic);
#pragma unroll
      for (int j = 0; j < 8; ++j) aA[j] += bits2f((unsigned short)v0[j]);
    }
    // drain B
    for (; iB + 2 <= cB; iB += 2) {
      int s0 = ssrc[stB + iB], s1 = ssrc[stB + iB + 1];
      short8 v0 = *(const short8*)(hc + (size_t)s0 * ic);
      short8 v1 = *(const short8*)(hc + (size_t)s1 * ic);
#pragma unroll
      for (int j = 0; j < 8; ++j)
        aB[j] += bits2f((unsigned short)v0[j]) + bits2f((unsigned short)v1[j]);
    }
    if (iB < cB) {
      int s0 = ssrc[stB + iB];
      short8 v0 = *(const short8*)(hc + (size_t)s0 * ic);
#pragma unroll
      for (int j = 0; j < 8; ++j) aB[j] += bits2f((unsigned short)v0[j]);
    }
    short8 oA, oB;
#pragma unroll
    for (int j = 0; j < 8; ++j) { oA[j] = f2bits(aA[j]); oB[j] = f2bits(aB[j]); }
    *(short8*)(agg + rowoff + rp * ic + cbase) = oA;
    *(short8*)(agg + rowoff + (rp + 4) * ic + cbase) = oB;
  }
}

// ---------------- split-N bf16 GEMM, bf16 out (conv layers): 128x64 tile, BK=128 ----------------
// Dual-source A: k0 < Kagg stages from AGG (stride Kagg); final ic-wide block
// stages from h directly (self/root operand never materialized).
__global__ __launch_bounds__(256) void gemm_f32_k(
    const bf16* __restrict__ A, const bf16* __restrict__ Hs,
    const bf16* __restrict__ Wt, bf16* __restrict__ Cb,
    int M, int N, int Kagg, int ic, int nb) {
  const int bid = blockIdx.x;
  const int xcd = bid & 7;
  const int slot = bid >> 3;
  const int gidx = slot / nb;
  const int member = slot - gidx * nb;
  const int mb = (M + 127) >> 7;
  const int m = gidx * 8 + xcd;
  if (m >= mb) return;
  const int m0 = m * 128;
  const int n0 = member * 64;
  const int K = Kagg + ic;    // weight K (9*ic)

  __shared__ __align__(16) bf16 As[128 * 128];
  __shared__ __align__(16) bf16 Ws[64 * 128];
  const int tid = threadIdx.x;
  const int wave = tid >> 6, lane = tid & 63;
  const int quad = lane >> 4, l16 = lane & 15;
  const int wm = (wave >> 1) * 64, wn = (wave & 1) * 32;
  floatx4 acc[4][2];
#pragma unroll
  for (int i = 0; i < 4; ++i)
#pragma unroll
    for (int j = 0; j < 2; ++j) acc[i][j] = (floatx4){0.f, 0.f, 0.f, 0.f};

  for (int k0 = 0; k0 < K; k0 += 128) {
    // As: 32 KB = 8 chunks/wave of 1 KB (4 rows x 16 slots each)
#pragma unroll
    for (int q = 0; q < 8; ++q) {
      int c0 = (wave * 8 + q) * 1024;
      int r = (c0 >> 8) + (lane >> 4);
      int grow = m0 + r; if (grow >= M) grow = M - 1;
      int s = lane & 15;
      int qg = ((s >> 3) << 3) | ((s & 7) ^ (r & 7));
      const bf16* src = (k0 < Kagg)
          ? (A + (size_t)grow * Kagg + k0 + qg * 8)
          : (Hs + (size_t)grow * ic + (k0 - Kagg) + qg * 8);
      async_copy16((char*)As + c0, src);
    }
    // Ws: 16 KB = 4 chunks/wave
#pragma unroll
    for (int q = 0; q < 4; ++q) {
      int c0 = (wave * 4 + q) * 1024;
      int r = (c0 >> 8) + (lane >> 4);
      int s = lane & 15;
      int qg = ((s >> 3) << 3) | ((s & 7) ^ (r & 7));
      async_copy16((char*)Ws + c0, Wt + (size_t)(n0 + r) * K + k0 + qg * 8);
    }
    __syncthreads();
#pragma unroll
    for (int kk = 0; kk < 4; ++kk) {
      int qg = kk * 4 + quad;
      short8 b0 = *(const short8*)(Ws + idx128(wn + l16, qg));
      short8 b1 = *(const short8*)(Ws + idx128(wn + 16 + l16, qg));
#pragma unroll
      for (int i = 0; i < 4; ++i) {
        short8 a = *(const short8*)(As + idx128(wm + i * 16 + l16, qg));
        acc[i][0] = __builtin_amdgcn_mfma_f32_16x16x32_bf16(a, b0, acc[i][0], 0, 0, 0);
        acc[i][1] = __builtin_amdgcn_mfma_f32_16x16x32_bf16(a, b1, acc[i][1], 0, 0, 0);
      }
    }
    __syncthreads();
  }
#pragma unroll
  for (int i = 0; i < 4; ++i)
#pragma unroll
    for (int j = 0; j < 2; ++j)
#pragma unroll
      for (int r = 0; r < 4; ++r) {
        int row = m0 + wm + i * 16 + quad * 4 + r;
        int col = n0 + wn + j * 16 + l16;
        if (row < M) Cb[(size_t)row * N + col] = f2b(acc[i][j][r]);
      }
}

// ---------------- plain bf16 GEMM (residuals, ZA): bf16 out, 64x64; grid (N/64, M/64) ----------------
__global__ __launch_bounds__(256) void gemm_plain_k(
    const bf16* __restrict__ A, const bf16* __restrict__ Wt,
    bf16* __restrict__ Cb, int M, int N, int K) {
  __shared__ __align__(16) bf16 As[64 * 64];
  __shared__ __align__(16) bf16 Ws[64 * 64];
  const int m0 = blockIdx.y * 64;
  const int n0 = blockIdx.x * 64;
  const int tid = threadIdx.x;
  const int wave = tid >> 6, lane = tid & 63;
  const int quad = lane >> 4, l16 = lane & 15;
  const int wm = (wave >> 1) * 32, wn = (wave & 1) * 32;
  floatx4 acc00 = {0.f, 0.f, 0.f, 0.f};
  floatx4 acc01 = acc00, acc10 = acc00, acc11 = acc00;

  for (int k0 = 0; k0 < K; k0 += 64) {
#pragma unroll
    for (int q = 0; q < 2; ++q) {
      int c0 = (wave * 2 + q) * 1024;
      int row = (c0 >> 7) + (lane >> 3);
      int grow = m0 + row; if (grow >= M) grow = M - 1;
      int ch = (lane & 7) ^ (row & 7);
      async_copy16((char*)As + c0, A + (size_t)grow * K + k0 + ch * 8);
    }
#pragma unroll
    for (int q = 0; q < 2; ++q) {
      int c0 = (wave * 2 + q) * 1024;
      int row = (c0 >> 7) + (lane >> 3);
      int ch = (lane & 7) ^ (row & 7);
      async_copy16((char*)Ws + c0, Wt + (size_t)(n0 + row) * K + k0 + ch * 8);
    }
    __syncthreads();
#pragma unroll
    for (int kk = 0; kk < 64; kk += 32) {
      int qb = (kk >> 3) + quad;
      short8 a0 = *frag_at(As, wm + l16, qb);
      short8 a1 = *frag_at(As, wm + 16 + l16, qb);
      short8 b0 = *frag_at(Ws, wn + l16, qb);
      short8 b1 = *frag_at(Ws, wn + 16 + l16, qb);
      acc00 = __builtin_amdgcn_mfma_f32_16x16x32_bf16(a0, b0, acc00, 0, 0, 0);
      acc01 = __builtin_amdgcn_mfma_f32_16x16x32_bf16(a0, b1, acc01, 0, 0, 0);
      acc10 = __builtin_amdgcn_mfma_f32_16x16x32_bf16(a1, b0, acc10, 0, 0, 0);
      acc11 = __builtin_amdgcn_mfma_f32_16x16x32_bf16(a1, b1, acc11, 0, 0, 0);
    }
    __syncthreads();
  }
  floatx4 accs[2][2] = {{acc00, acc01}, {acc10, acc11}};
#pragma unroll
  for (int i = 0; i < 2; ++i)
#pragma unroll
    for (int j = 0; j < 2; ++j)
#pragma unroll
      for (int r = 0; r < 4; ++r) {
        int row = m0 + wm + i * 16 + quad * 4 + r;
        int col = n0 + wn + j * 16 + l16;
        if (row < M) Cb[(size_t)row * N + col] = f2b(accs[i][j][r]);
      }
}

// ---------------- LN (+residual, +gelu) for conv layers ----------------
__global__ __launch_bounds__(256) void ln_conv_k(
    const bf16* __restrict__ conv, const bf16* __restrict__ res,
    const float* __restrict__ g, const float* __restrict__ b,
    bf16* __restrict__ out, float* __restrict__ zout, int oc, int do_gelu) {
  const int lprsh = (oc == 256) ? 5 : 4;       // lanes per row = oc/8
  const int lpr = 1 << lprsh;
  const int rpb = 256 >> lprsh;
  int row = blockIdx.x * rpb + (threadIdx.x >> lprsh);
  if (row >= NN) return;
  int cb = (threadIdx.x & (lpr - 1)) * 8;
  short8 cv = *(const short8*)(conv + (size_t)row * oc + cb);
  float v[8];
  float s = 0.f, s2 = 0.f;
#pragma unroll
  for (int j = 0; j < 8; ++j) {
    v[j] = bits2f((unsigned short)cv[j]);
    s += v[j]; s2 += v[j] * v[j];
  }
  for (int off = lpr >> 1; off; off >>= 1) { s += __shfl_xor(s, off); s2 += __shfl_xor(s2, off); }
  float m = s / oc;
  float var = s2 / oc - m * m;
  float rs = rsqrtf(var + 1e-5f);
  short8 rv = *(const short8*)(res + (size_t)row * oc + cb);
  short8 ov;
#pragma unroll
  for (int j = 0; j < 8; ++j) {
    int c = cb + j;
    float y = (v[j] - m) * rs * g[c] + b[c];
    y += bits2f((unsigned short)rv[j]);
    if (zout) zout[(size_t)row * oc + c] = y;
    if (do_gelu) y = gelu_f(y);
    ov[j] = f2bits(y);
  }
  *(short8*)(out + (size_t)row * oc + cb) = ov;
}

// ---------------- decoder GEMM0 (nb=2, combined-K, XCD-pinned) ----------------
__global__ __launch_bounds__(256) void gemm_pe_k(
    const bf16* __restrict__ z, const int* __restrict__ pairs,
    const bf16* __restrict__ WPE,  // [256 out][256 K]  (K = prod128 | diff128)
    bf16* __restrict__ P0) {
  const int bid = blockIdx.x;
  const int xcd = bid & 7;
  const int slot = bid >> 3;
  const int gidx = slot >> 1;          // nb = 2
  const int member = slot & 1;
  const int mb = (PP + 127) >> 7;
  const int m = gidx * 8 + xcd;
  if (m >= mb) return;
  const int m0 = m * 128;
  const int n0 = member * 128;

  __shared__ __align__(16) bf16 PEs[128 * 128];
  __shared__ __align__(16) bf16 Ws[128 * 128];
  const int tid = threadIdx.x;
  const int wave = tid >> 6, lane = tid & 63;
  const int quad = lane >> 4, l16 = lane & 15;
  const int wm = (wave >> 1) * 64, wn = (wave & 1) * 64;

  const int prow = tid >> 1;           // 0..127
  const int h = tid & 1;               // 32-col half of the 64-col z chunk
  int pp = m0 + prow; if (pp >= PP) pp = PP - 1;
  const bf16* zi = z + (size_t)pairs[pp] * 128;
  const bf16* zj = z + (size_t)pairs[PP + pp] * 128;

  floatx4 acc[4][4];
#pragma unroll
  for (int i = 0; i < 4; ++i)
#pragma unroll
    for (int j = 0; j < 4; ++j) acc[i][j] = (floatx4){0.f, 0.f, 0.f, 0.f};

#pragma unroll
  for (int kwi = 0; kwi < 2; ++kwi) {
    const int kw = kwi * 64;
    short8 va[4], vb[4];
#pragma unroll
    for (int c8 = 0; c8 < 4; ++c8) {
      va[c8] = *(const short8*)(zi + kw + h * 32 + c8 * 8);
      vb[c8] = *(const short8*)(zj + kw + h * 32 + c8 * 8);
    }
    if (kwi) __syncthreads();
#pragma unroll
    for (int q = 0; q < 8; ++q) {
      int c0 = (wave * 8 + q) * 1024;
      int r = (c0 >> 8) + (lane >> 4);
      int s = lane & 15;
      async_copy16((char*)Ws + c0,
                   WPE + (size_t)(n0 + r) * 256 + ((s >> 3) << 7) + kw + (((s & 7) ^ (r & 7)) << 3));
    }
#pragma unroll
    for (int c8 = 0; c8 < 4; ++c8) {
      short8 op, od;
#pragma unroll
      for (int jj = 0; jj < 8; ++jj) {
        float fa = bits2f((unsigned short)va[c8][jj]);
        float fb = bits2f((unsigned short)vb[c8][jj]);
        op[jj] = f2bits(fa * fb);
        od[jj] = f2bits(fabsf(fa - fb));
      }
      *(short8*)(PEs + idx128(prow, h * 4 + c8)) = op;
      *(short8*)(PEs + idx128(prow, 8 + h * 4 + c8)) = od;
    }
    __syncthreads();
#pragma unroll
    for (int ks = 0; ks < 4; ++ks) {
      const int qg = ks * 4 + quad;
      short8 bfr[4];
#pragma unroll
      for (int j = 0; j < 4; ++j)
        bfr[j] = *(const short8*)(Ws + idx128(wn + j * 16 + l16, qg));
#pragma unroll
      for (int i = 0; i < 4; ++i) {
        short8 a = *(const short8*)(PEs + idx128(wm + i * 16 + l16, qg));
#pragma unroll
        for (int j = 0; j < 4; ++j)
          acc[i][j] = __builtin_amdgcn_mfma_f32_16x16x32_bf16(a, bfr[j], acc[i][j], 0, 0, 0);
      }
    }
  }

#pragma unroll
  for (int i = 0; i < 4; ++i)
#pragma unroll
    for (int j = 0; j < 4; ++j)
#pragma unroll
      for (int r = 0; r < 4; ++r) {
        int row = m0 + wm + i * 16 + quad * 4 + r;
        int col = n0 + wn + j * 16 + l16;
        if (row < PP) P0[(size_t)row * 256 + col] = f2b(acc[i][j][r]);
      }
}

// ---------------- elementwise: D0 = gelu(ln(P0 + ZA[gi] + ZA[gj] + db0)) in place ----------------
__global__ __launch_bounds__(256) void ln_d0_k(bf16* __restrict__ D0,
                                               const int* __restrict__ pairs,
                                               const bf16* __restrict__ ZA,
                                               const float* __restrict__ db0,
                                               const float* __restrict__ g,
                                               const float* __restrict__ b) {
  const int wave = threadIdx.x >> 6, lane = threadIdx.x & 63;
  const int row = blockIdx.x * 8 + wave * 2 + (lane >> 5);   // PP % 8 == 0
  const int cb = (lane & 31) * 8;
  int gi = pairs[row], gj = pairs[PP + row];
  bf16* p = D0 + (size_t)row * 256 + cb;
  short8 xv = *(const short8*)p;
  short8 av = *(const short8*)(ZA + (size_t)gi * 256 + cb);
  short8 bv = *(const short8*)(ZA + (size_t)gj * 256 + cb);
  float v[8];
  float s = 0.f, s2 = 0.f;
#pragma unroll
  for (int k = 0; k < 8; ++k) {
    v[k] = bits2f((unsigned short)xv[k]) + bits2f((unsigned short)av[k]) +
           bits2f((unsigned short)bv[k]) + db0[cb + k];
    s += v[k]; s2 += v[k] * v[k];
  }
  for (int off = 16; off; off >>= 1) { s += __shfl_xor(s, off); s2 += __shfl_xor(s2, off); }
  float m = s / 256.f;
  float var = s2 / 256.f - m * m;
  float rs = rsqrtf(var + 1e-5f);
  short8 ov;
#pragma unroll
  for (int k = 0; k < 8; ++k) {
    float y = (v[k] - m) * rs * g[cb + k] + b[cb + k];
    ov[k] = f2bits(gelu_f(y));
  }
  *(short8*)p = ov;
}

// ---------------- decoder GEMM1: A = D0 (bf16) staged; P1 = A@W1^T + db1 ----------------
__global__ __launch_bounds__(256) void lngemm1_k(
    const bf16* __restrict__ D0, const bf16* __restrict__ W1t,  // [128][256]
    const float* __restrict__ bias, bf16* __restrict__ P1, int M) {
  __shared__ __align__(16) bf16 As[64 * 256];
  __shared__ __align__(16) bf16 Ws[128 * 64];
  const int tid = threadIdx.x;
  const int wave = tid >> 6, lane = tid & 63;
  const int quad = lane >> 4, l16 = lane & 15;
  const int wr = (wave >> 1) * 32;
  const int wc = (wave & 1) * 64;
  const int m0 = blockIdx.x * 64;

  {
    const int srow = tid >> 2;
    const int q4 = tid & 3;
    int grow = m0 + srow; if (grow >= M) grow = M - 1;
    const bf16* src = D0 + (size_t)grow * 256 + q4 * 64;
#pragma unroll
    for (int c8 = 0; c8 < 8; ++c8) {
      short8 o = *(const short8*)(src + c8 * 8);
      *(short8*)(As + srow * 256 + q4 * 64 + ((c8 ^ (srow & 7)) << 3)) = o;
    }
  }

  floatx4 acc[2][4];
#pragma unroll
  for (int i = 0; i < 2; ++i)
#pragma unroll
    for (int j = 0; j < 4; ++j) acc[i][j] = (floatx4){0.f, 0.f, 0.f, 0.f};

  for (int kc = 0; kc < 4; ++kc) {
#pragma unroll
    for (int q = 0; q < 4; ++q) {
      int c0 = q * 4096 + wave * 1024;
      int row = (c0 >> 7) + (lane >> 3);
      int ch = (lane & 7) ^ (row & 7);
      async_copy16((char*)Ws + c0, W1t + (size_t)row * 256 + kc * 64 + ch * 8);
    }
    __syncthreads();
#pragma unroll
    for (int kk = 0; kk < 64; kk += 32) {
      int qb = (kk >> 3) + quad;
      short8 a0 = *frag256(As, wr + l16, kc * 64, qb);
      short8 a1 = *frag256(As, wr + 16 + l16, kc * 64, qb);
#pragma unroll
      for (int j = 0; j < 4; ++j) {
        short8 bb = *frag_at(Ws, wc + j * 16 + l16, qb);
        acc[0][j] = __builtin_amdgcn_mfma_f32_16x16x32_bf16(a0, bb, acc[0][j], 0, 0, 0);
        acc[1][j] = __builtin_amdgcn_mfma_f32_16x16x32_bf16(a1, bb, acc[1][j], 0, 0, 0);
      }
    }
    __syncthreads();
  }

#pragma unroll
  for (int i = 0; i < 2; ++i)
#pragma unroll
    for (int r = 0; r < 4; ++r) {
      int row = wr + i * 16 + quad * 4 + r;
      int grow = m0 + row;
      if (grow >= M) continue;
#pragma unroll
      for (int j = 0; j < 4; ++j) {
        int col = wc + j * 16 + l16;
        P1[(size_t)grow * 128 + col] = f2b(acc[i][j][r] + bias[col]);
      }
    }
}

// ---------------- decoder GEMM2 + logits (fused) ----------------
__global__ __launch_bounds__(256) void lngemm2_k(
    const bf16* __restrict__ P1, const bf16* __restrict__ W2t,  // [64][128]
    const float* __restrict__ g, const float* __restrict__ b,
    const float* __restrict__ bias,
    const float* __restrict__ g2, const float* __restrict__ b2,
    const float* __restrict__ w3, const float* __restrict__ b3,
    float* __restrict__ out, int M) {
  __shared__ __align__(16) bf16 As[64 * 128];
  __shared__ __align__(16) bf16 Ws[64 * 64];
  const int tid = threadIdx.x;
  const int wave = tid >> 6, lane = tid & 63;
  const int quad = lane >> 4, l16 = lane & 15;
  const int m0 = blockIdx.x * 64;

  {
    const int srow = tid >> 2;
    const int q4 = tid & 3;
    int grow = m0 + srow; if (grow >= M) grow = M - 1;
    const bf16* src = P1 + (size_t)grow * 128 + q4 * 32;
    float v[32];
    float s = 0.f, s2 = 0.f;
#pragma unroll
    for (int c8 = 0; c8 < 4; ++c8) {
      short8 x = *(const short8*)(src + c8 * 8);
#pragma unroll
      for (int jj = 0; jj < 8; ++jj) {
        float f = bits2f((unsigned short)x[jj]);
        v[c8 * 8 + jj] = f; s += f; s2 += f * f;
      }
    }
    s += __shfl_xor(s, 1); s2 += __shfl_xor(s2, 1);
    s += __shfl_xor(s, 2); s2 += __shfl_xor(s2, 2);
    float mean = s / 128.f;
    float var = s2 / 128.f - mean * mean;
    float rs = rsqrtf(var + 1e-5f);
#pragma unroll
    for (int c8 = 0; c8 < 4; ++c8) {
      short8 o;
#pragma unroll
      for (int jj = 0; jj < 8; ++jj) {
        int col = q4 * 32 + c8 * 8 + jj;
        float y = (v[c8 * 8 + jj] - mean) * rs * g[col] + b[col];
        o[jj] = f2bits(gelu_f(y));
      }
      *(short8*)(As + idx128(srow, q4 * 4 + c8)) = o;
    }
  }

  floatx4 acc[4];
#pragma unroll
  for (int j = 0; j < 4; ++j) acc[j] = (floatx4){0.f, 0.f, 0.f, 0.f};

  for (int kc = 0; kc < 2; ++kc) {
#pragma unroll
    for (int q = 0; q < 2; ++q) {
      int c0 = q * 4096 + wave * 1024;
      int row = (c0 >> 7) + (lane >> 3);
      int ch = (lane & 7) ^ (row & 7);
      async_copy16((char*)Ws + c0, W2t + (size_t)row * 128 + kc * 64 + ch * 8);
    }
    __syncthreads();
#pragma unroll
    for (int kk = 0; kk < 64; kk += 32) {
      int qb = (kk >> 3) + quad;
      short8 a = *(const short8*)(As + idx128(wave * 16 + l16, kc * 8 + qb));
#pragma unroll
      for (int j = 0; j < 4; ++j) {
        short8 bb = *frag_at(Ws, j * 16 + l16, qb);
        acc[j] = __builtin_amdgcn_mfma_f32_16x16x32_bf16(a, bb, acc[j], 0, 0, 0);
      }
    }
    __syncthreads();
  }

#pragma unroll
  for (int r = 0; r < 4; ++r) {
    int row = wave * 16 + quad * 4 + r;
    int grow = m0 + row;
    float y[4];
    float s = 0.f, s2 = 0.f;
#pragma unroll
    for (int j = 0; j < 4; ++j) {
      int col = j * 16 + l16;
      y[j] = acc[j][r] + bias[col];
      s += y[j]; s2 += y[j] * y[j];
    }
    for (int off = 8; off; off >>= 1) { s += __shfl_xor(s, off); s2 += __shfl_xor(s2, off); }
    float mean = s / 64.f;
    float var = s2 / 64.f - mean * mean;
    float rs = rsqrtf(var + 1e-5f);
    float t = 0.f;
#pragma unroll
    for (int j = 0; j < 4; ++j) {
      int col = j * 16 + l16;
      float yy = gelu_f((y[j] - mean) * rs * g2[col] + b2[col]);
      t += yy * w3[col];
    }
    for (int off = 8; off; off >>= 1) t += __shfl_xor(t, off);
    if (l16 == 0 && grow < M) out[grow] = t + b3[0];
  }
}

// ---------------- host ----------------
extern "C" void kernel_launch(void* const* d_in, const int* in_sizes, int n_in,
                              void* d_out, int out_size, void* d_ws, size_t ws_size,
                              hipStream_t stream) {
  auto cdiv = [](int a, int b) { return (a + b - 1) / b; };

  const float* x = (const float*)d_in[0];
  const int* ei = (const int*)d_in[1];
  const int* et = (const int*)d_in[2];
  const int* gp = (const int*)d_in[3];
  const float *basis[4], *att[4], *root[4], *relatt[4], *gln[4], *bln[4];
  for (int l = 0; l < 4; ++l) {
    basis[l]  = (const float*)d_in[4 + 6 * l];
    att[l]    = (const float*)d_in[5 + 6 * l];
    root[l]   = (const float*)d_in[6 + 6 * l];
    relatt[l] = (const float*)d_in[7 + 6 * l];
    gln[l]    = (const float*)d_in[8 + 6 * l];
    bln[l]    = (const float*)d_in[9 + 6 * l];
  }
  const float* res0 = (const float*)d_in[28];
  const float* res3 = (const float*)d_in[29];
  const float* dW0 = (const float*)d_in[30]; const float* db0 = (const float*)d_in[31];
  const float* dg0 = (const float*)d_in[32]; const float* dbb0 = (const float*)d_in[33];
  const float* dW1 = (const float*)d_in[34]; const float* db1 = (const float*)d_in[35];
  const float* dg1 = (const float*)d_in[36]; const float* dbb1 = (const float*)d_in[37];
  const float* dW2 = (const float*)d_in[38]; const float* db2 = (const float*)d_in[39];
  const float* dg2 = (const float*)d_in[40]; const float* dbb2 = (const float*)d_in[41];
  const float* dW3 = (const float*)d_in[42]; const float* db3 = (const float*)d_in[43];

  char* base = (char*)d_ws;
  size_t off = 0;
  auto alloc = [&](size_t bytes) -> char* {
    char* p = base + off;
    off += (bytes + 255) & ~(size_t)255;
    return p;
  };
  bf16* X16 = (bf16*)alloc((size_t)NN * 128 * 2);
  bf16* HA  = (bf16*)alloc((size_t)NN * 256 * 2);
  bf16* HB  = (bf16*)alloc((size_t)NN * 256 * 2);
  bf16* RESB = (bf16*)alloc((size_t)NN * 256 * 2);
  bf16* ZA   = (bf16*)alloc((size_t)NN * 256 * 2);
  bf16* CONV = (bf16*)alloc((size_t)NN * 256 * 2);
  bf16* WT0  = (bf16*)alloc((size_t)294912 * 2);
  bf16* WT1  = (bf16*)alloc((size_t)589824 * 2);
  bf16* WT2  = (bf16*)alloc((size_t)589824 * 2);
  bf16* WT3  = (bf16*)alloc((size_t)294912 * 2);
  bf16* RES0T = (bf16*)alloc((size_t)32768 * 2);
  bf16* RES3T = (bf16*)alloc((size_t)32768 * 2);
  bf16* WAT   = (bf16*)alloc((size_t)32768 * 2);
  bf16* WPE   = (bf16*)alloc((size_t)65536 * 2);   // [256][256] combined prod|diff W^T
  bf16* DW1T  = (bf16*)alloc((size_t)32768 * 2);
  bf16* DW2T  = (bf16*)alloc((size_t)8192 * 2);
  int* COUNTS = (int*)alloc((size_t)NR * 4);       // NR*4 is 256-aligned ->
  int* CUR    = (int*)alloc((size_t)NR * 4);       // COUNTS/CUR contiguous (1 memset)
  int* SEG    = (int*)alloc((size_t)NR * 4);
  int* BS     = (int*)alloc(1024 * 4);
  int* SSRC   = (int*)alloc((size_t)EE * 4);
  char* BIG = alloc(93000000);   // overlay: AGG [N,2048]bf16 (82MB) | P0/D0 [P,256]bf16 (51.2MB)
  bf16* AGG = (bf16*)BIG;
  bf16* P0  = (bf16*)BIG;
  bf16* P1  = (bf16*)alloc((size_t)PP * 128 * 2);
  (void)ws_size; (void)in_sizes; (void)n_in; (void)out_size;

  float* out_logits = (float*)d_out;
  float* out_z = (float*)d_out + PP;

  // --- CSR build ---
  hipMemsetAsync(COUNTS, 0, (size_t)2 * NR * 4, stream);   // COUNTS + CUR
  hist_k<<<cdiv(EE, 256), 256, 0, stream>>>(ei + EE, et, COUNTS);
  scan1_k<<<NR / 256, 256, 0, stream>>>(COUNTS, SEG, BS);
  scan2_k<<<1, 256, 0, stream>>>(BS, NR / 256);
  scan3_k<<<NR / 256, 256, 0, stream>>>(SEG, BS);
  scatter_k<<<cdiv(EE, 256), 256, 0, stream>>>(ei, ei + EE, et, SEG, CUR, SSRC);

  // --- weight prep (all up front) ---
  cvt_bf16_k<<<cdiv(NN * 128, 256), 256, 0, stream>>>(x, X16, NN * 128);
  prep_small_k<<<cdiv(172032, 256), 256, 0, stream>>>(res0, res3, dW0, dW1, dW2,
                                                      RES0T, RES3T, WAT, WPE, DW1T, DW2T);
  prep_w_all_k<<<cdiv(196608, 256), 256, 0, stream>>>(
      basis[0], att[0], root[0], relatt[0],
      basis[1], att[1], root[1], relatt[1],
      basis[2], att[2], root[2], relatt[2],
      basis[3], att[3], root[3], relatt[3],
      WT0, WT1, WT2, WT3);

  const int mb = cdiv(NN, 128);            // 157
  const int swzP4 = 8 * cdiv(mb, 8) * 4;   // nb=4
  const int swzP2 = 8 * cdiv(mb, 8) * 2;   // nb=2

  // --- layer 0: ic=128, oc=256, residual = x @ res0 ---
  aggregate_k<<<cdiv(NN, 16), 256, 0, stream>>>(X16, SEG, COUNTS, SSRC, AGG, 128, 4);
  gemm_plain_k<<<dim3(4, cdiv(NN, 64)), 256, 0, stream>>>(X16, RES0T, RESB, NN, 256, 128);
  gemm_f32_k<<<swzP4, 256, 0, stream>>>(AGG, X16, WT0, CONV, NN, 256, 1024, 128, 4);
  ln_conv_k<<<cdiv(NN, 8), 256, 0, stream>>>(CONV, RESB, gln[0], bln[0], HA, nullptr, 256, 1);

  // --- layer 1 ---
  aggregate_k<<<cdiv(NN, 8), 256, 0, stream>>>(HA, SEG, COUNTS, SSRC, AGG, 256, 5);
  gemm_f32_k<<<swzP4, 256, 0, stream>>>(AGG, HA, WT1, CONV, NN, 256, 2048, 256, 4);
  ln_conv_k<<<cdiv(NN, 8), 256, 0, stream>>>(CONV, HA, gln[1], bln[1], HB, nullptr, 256, 1);

  // --- layer 2 ---
  aggregate_k<<<cdiv(NN, 8), 256, 0, stream>>>(HB, SEG, COUNTS, SSRC, AGG, 256, 5);
  gemm_f32_k<<<swzP4, 256, 0, stream>>>(AGG, HB, WT2, CONV, NN, 256, 2048, 256, 4);
  ln_conv_k<<<cdiv(NN, 8), 256, 0, stream>>>(CONV, HB, gln[2], bln[2], HA, nullptr, 256, 1);

  // --- layer 3: oc=128, residual = h_in @ res3, no gelu; writes z (fp32 out_z) + HB ---
  aggregate_k<<<cdiv(NN, 8), 256, 0, stream>>>(HA, SEG, COUNTS, SSRC, AGG, 256, 5);
  gemm_plain_k<<<dim3(2, cdiv(NN, 64)), 256, 0, stream>>>(HA, RES3T, RESB, NN, 128, 256);
  gemm_f32_k<<<swzP2, 256, 0, stream>>>(AGG, HA, WT3, CONV, NN, 128, 2048, 256, 2);
  ln_conv_k<<<cdiv(NN, 16), 256, 0, stream>>>(CONV, RESB, gln[3], bln[3], HB, out_z, 128, 0);

  // --- decoder ---
  gemm_plain_k<<<dim3(4, cdiv(NN, 64)), 256, 0, stream>>>(HB, WAT, ZA, NN, 256, 128);
  const int pb = cdiv(PP, 128);            // 782
  const int swzPE = 8 * cdiv(pb, 8) * 2;   // nb=2
  gemm_pe_k<<<swzPE, 256, 0, stream>>>(HB, gp, WPE, P0);
  ln_d0_k<<<cdiv(PP, 8), 256, 0, stream>>>(P0, gp, ZA, db0, dg0, dbb0);
  lngemm1_k<<<cdiv(PP, 64), 256, 0, stream>>>(P0, DW1T, db1, P1, PP);
  lngemm2_k<<<cdiv(PP, 64), 256, 0, stream>>>(P1, DW2T, dg1, dbb1, db2, dg2, dbb2,
                                              dW3, db3, out_logits, PP);
}